// Round 3
// baseline (364.484 us; speedup 1.0000x reference)
//
#include <hip/hip_runtime.h>

// ---------------------------------------------------------------------------
// HFLongFormerSelfAttentionBlock — MI355X implementation (round 9)
//
// I/O fp32; internal bf16 MFMA, fp32 accumulation/epilogues.
// Round-9: gemm_bt epilogue rewritten — the old one did 64 scalar 2-B global
// stores per thread (rocprof: WRITE_SIZE 72 MB vs 33.5 ideal = 2.15x write
// amplification; MfmaUtil 13% => ~65us of the 103us MLP1 dispatch was
// epilogue). Now the C tile is staged in LDS (reusing As/Bs, 136-short row
// stride for 16-B alignment) and written with 8 coalesced bf16x8 stores per
// thread. Applies to mode 1 (gelu) and mode 0 Q/K segments; Vt scatter
// unchanged. MLP2 stays split-K x4 with atomic fp32 accumulate (round 8).
// ---------------------------------------------------------------------------

using bf16x8 = __attribute__((ext_vector_type(8))) short;
using bf16x4 = __attribute__((ext_vector_type(4))) short;
using f32x4  = __attribute__((ext_vector_type(4))) float;

__device__ __forceinline__ float b2f(short s) {
    return __uint_as_float(((unsigned int)(unsigned short)s) << 16);
}
__device__ __forceinline__ short f2b(float f) {
    unsigned int u = __float_as_uint(f);
    u += 0x7fffu + ((u >> 16) & 1u);   // round-to-nearest-even
    return (short)(u >> 16);
}
__device__ __forceinline__ f32x4 mfma16(bf16x8 a, bf16x8 b, f32x4 c) {
    return __builtin_amdgcn_mfma_f32_16x16x32_bf16(a, b, c, 0, 0, 0);
}
__device__ __forceinline__ float safe_exp(float x) {
    return expf((x <= 0.f) ? x : 0.f);
}
// async global->LDS, 16 B per lane; LDS dest = wave-uniform base + lane*16
__device__ __forceinline__ void load_lds16(const short* g, short* l) {
    __builtin_amdgcn_global_load_lds((const __attribute__((address_space(1))) void*)g,
                                     (__attribute__((address_space(3))) void*)l, 16, 0, 0);
}
#define NEGF (-3.0e38f)

// ---------------------------------------------------------------------------
// fp32 -> bf16 elementwise convert (n multiple of 1024). grid n/1024, 256 thr
// ---------------------------------------------------------------------------
__global__ void cvt_f32_bf16(const float* __restrict__ in, short* __restrict__ out, int n) {
    int i = (blockIdx.x * 256 + threadIdx.x) * 4;
    f32x4 v = *(const f32x4*)(in + i);
    bf16x4 o;
#pragma unroll
    for (int j = 0; j < 4; ++j) o[j] = f2b(v[j]);
    *(bf16x4*)(out + i) = o;
}

// ---------------------------------------------------------------------------
// fp32 in, bf16 transposed out: out[c][r] = in[r][c], in is R x C.
// grid (C/32, R/32), block (32,8)
// ---------------------------------------------------------------------------
__global__ void cvt_transpose(const float* __restrict__ in, short* __restrict__ out,
                              int R, int C) {
    __shared__ short tile[32][33];
    int bx = blockIdx.x * 32, by = blockIdx.y * 32;
    int tx = threadIdx.x, ty = threadIdx.y;
    for (int i = ty; i < 32; i += 8)
        tile[i][tx] = f2b(in[(size_t)(by + i) * C + bx + tx]);
    __syncthreads();
    for (int i = ty; i < 32; i += 8)
        out[(size_t)(bx + i) * R + by + tx] = tile[tx][i];
}

// wq/wk/wv (each 1024x1024 fp32) -> WQKVT (3072x1024 bf16, = [wq^T;wk^T;wv^T])
__global__ void cvt_transpose_qkv(const float* __restrict__ wq, const float* __restrict__ wk,
                                  const float* __restrict__ wv, short* __restrict__ out) {
    __shared__ short tile[32][33];
    const float* in = (blockIdx.z == 0) ? wq : (blockIdx.z == 1) ? wk : wv;
    short* dst = out + (size_t)blockIdx.z * 1024 * 1024;
    int bx = blockIdx.x * 32, by = blockIdx.y * 32;
    int tx = threadIdx.x, ty = threadIdx.y;
    for (int i = ty; i < 32; i += 8)
        tile[i][tx] = f2b(in[(size_t)(by + i) * 1024 + bx + tx]);
    __syncthreads();
    for (int i = ty; i < 32; i += 8)
        dst[(size_t)(bx + i) * 1024 + by + tx] = tile[tx][i];
}

// ---------------------------------------------------------------------------
// GEMM 128x128, BK=64, XOR-swizzled LDS k-chunks.
// LDS layout: L[row][slot] = G[row][slot ^ (row&7)]  (slot/chunk = 8 shorts).
// Staging lane i of chunk c: row = c*8 + (i>>3), global k-chunk (i&7)^(i>>3).
// Frag read (row, k-chunk t): LDS addr = row*64 + (t ^ (row&7))*8 shorts.
// mode 0: QKV — bias bq/bk/bv by col segment, Q scaled, V written to Vt(b,h,d,s)
// mode 1: C = bf16(gelu(acc + bias0[col]))
// Epilogue (mode 1 / mode 0 seg<2): stage tile in LDS (stride 136 shorts),
// then 8 coalesced bf16x8 stores per thread.
// ---------------------------------------------------------------------------
__global__ __launch_bounds__(256, 3) void gemm_bt(
    const short* __restrict__ A, const short* __restrict__ Bt,
    const float* __restrict__ bias0, const float* __restrict__ bias1,
    const float* __restrict__ bias2,
    short* __restrict__ C, short* __restrict__ Vt,
    int M, int N, int K, float scale, int mode)
{
    __shared__ short sh[128 * 136];   // 34.8 KB; main loop uses first 16K shorts
    short* As = sh;
    short* Bs = sh + 8192;
    int m0 = blockIdx.x * 128, n0 = blockIdx.y * 128;
    int t = threadIdx.x;
    int wave = t >> 6, lane = t & 63, quad = lane >> 4, l16 = lane & 15;
    int wr = (wave >> 1) * 64, wc = (wave & 1) * 64;

    // staging pointers: 4 chunks per wave per buffer
    const short* ap[4]; const short* bp[4]; short* la[4]; short* lb[4];
    int gk = (((lane & 7) ^ (lane >> 3)) * 8);
#pragma unroll
    for (int l = 0; l < 4; ++l) {
        int c = wave * 4 + l;
        int row = c * 8 + (lane >> 3);
        ap[l] = A  + (size_t)(m0 + row) * K + gk;
        bp[l] = Bt + (size_t)(n0 + row) * K + gk;
        la[l] = As + c * 512;
        lb[l] = Bs + c * 512;
    }
    int sw = l16 & 7;   // frag-read swizzle key

    f32x4 acc[4][4] = {};
    for (int k0 = 0; k0 < K; k0 += 64) {
#pragma unroll
        for (int l = 0; l < 4; ++l) { load_lds16(ap[l] + k0, la[l]); load_lds16(bp[l] + k0, lb[l]); }
        __syncthreads();
#pragma unroll
        for (int ks = 0; ks < 2; ++ks) {
            int slot = ((ks * 4 + quad) ^ sw) * 8;
            bf16x8 af[4], bfr[4];
#pragma unroll
            for (int i = 0; i < 4; ++i)
                af[i] = *(bf16x8*)(As + (wr + i * 16 + l16) * 64 + slot);
#pragma unroll
            for (int j = 0; j < 4; ++j)
                bfr[j] = *(bf16x8*)(Bs + (wc + j * 16 + l16) * 64 + slot);
#pragma unroll
            for (int i = 0; i < 4; ++i)
#pragma unroll
                for (int j = 0; j < 4; ++j)
                    acc[i][j] = mfma16(af[i], bfr[j], acc[i][j]);
        }
        __syncthreads();
    }
    // after final barrier, all LDS reads are done -> sh reusable for staging

    int seg0 = n0 >> 10;   // tiles are 128-aligned: never straddle a segment
    if (mode == 1 || seg0 < 2) {
        // ---- stage bf16 tile in LDS: sh[row*136 + col], row/col in [0,128)
        if (mode == 1) {
#pragma unroll
            for (int j = 0; j < 4; ++j) {
                int col = n0 + wc + j * 16 + l16;
                float bs = bias0[col];
#pragma unroll
                for (int i = 0; i < 4; ++i)
#pragma unroll
                    for (int r = 0; r < 4; ++r) {
                        float v = acc[i][j][r] + bs;
                        v = 0.5f * v * (1.0f + erff(v * 0.70710678118f));
                        sh[(wr + i * 16 + quad * 4 + r) * 136 + wc + j * 16 + l16] = f2b(v);
                    }
            }
        } else {
            float sc = (seg0 == 0) ? scale : 1.0f;
            const float* bpt = (seg0 == 0) ? bias0 : bias1;
#pragma unroll
            for (int j = 0; j < 4; ++j) {
                int col = n0 + wc + j * 16 + l16;
                float bs = bpt[col & 1023];
#pragma unroll
                for (int i = 0; i < 4; ++i)
#pragma unroll
                    for (int r = 0; r < 4; ++r)
                        sh[(wr + i * 16 + quad * 4 + r) * 136 + wc + j * 16 + l16] =
                            f2b((acc[i][j][r] + bs) * sc);
            }
        }
        __syncthreads();
        // ---- coalesced write-out: 2 threads per row, 8 x 16 B each
        int row = t >> 1, half = t & 1;
        const short* src = sh + row * 136 + half * 64;
        short* dst = C + (size_t)(m0 + row) * N + n0 + half * 64;
#pragma unroll
        for (int cgk = 0; cgk < 8; ++cgk)
            *(bf16x8*)(dst + cgk * 8) = *(const bf16x8*)(src + cgk * 8);
    } else {
        // V part -> Vt (b, h, d, s), 4 consecutive s per thread (8-B stores)
#pragma unroll
        for (int j = 0; j < 4; ++j) {
            int col = n0 + wc + j * 16 + l16;
            float bs = bias2[col & 1023];
            int h = (col >> 6) & 15, d = col & 63;
#pragma unroll
            for (int i = 0; i < 4; ++i) {
                int row0 = m0 + wr + i * 16 + quad * 4;
                int bb = row0 >> 11, s0 = row0 & 2047;
                bf16x4 vv;
#pragma unroll
                for (int r = 0; r < 4; ++r) vv[r] = f2b(acc[i][j][r] + bs);
                *(bf16x4*)(Vt + (((size_t)(bb * 16 + h)) * 64 + d) * 2048 + s0) = vv;
            }
        }
    }
}

// ---------------------------------------------------------------------------
// GEMM 128x128, BK=64, SPLIT-K: blockIdx.z selects a K-range of length KS.
// Same single-buffer 2-barrier structure + XOR swizzle as gemm_bt.
// Epilogue: fp32 atomicAdd into Cf, which resid_ln pre-filled with y + b2.
// grid (M/128, N/128, K/KS), 256 thr, 32 KB LDS.
// ---------------------------------------------------------------------------
__global__ __launch_bounds__(256, 3) void gemm128_sk(
    const short* __restrict__ A, const short* __restrict__ Bt,
    float* __restrict__ Cf, int M, int N, int K, int KS)
{
    __shared__ short As[128 * 64];
    __shared__ short Bs[128 * 64];
    int m0 = blockIdx.x * 128, n0 = blockIdx.y * 128;
    int t = threadIdx.x;
    int wave = t >> 6, lane = t & 63, quad = lane >> 4, l16 = lane & 15;
    int wr = (wave >> 1) * 64, wc = (wave & 1) * 64;

    const short* ap[4]; const short* bp[4]; short* la[4]; short* lb[4];
    int gk = (((lane & 7) ^ (lane >> 3)) * 8);
#pragma unroll
    for (int l = 0; l < 4; ++l) {
        int c = wave * 4 + l;
        int row = c * 8 + (lane >> 3);
        ap[l] = A  + (size_t)(m0 + row) * K + gk;
        bp[l] = Bt + (size_t)(n0 + row) * K + gk;
        la[l] = As + c * 512;
        lb[l] = Bs + c * 512;
    }
    int sw = l16 & 7;

    int kbeg = blockIdx.z * KS, kend = kbeg + KS;
    f32x4 acc[4][4] = {};
    for (int k0 = kbeg; k0 < kend; k0 += 64) {
#pragma unroll
        for (int l = 0; l < 4; ++l) { load_lds16(ap[l] + k0, la[l]); load_lds16(bp[l] + k0, lb[l]); }
        __syncthreads();
#pragma unroll
        for (int ks = 0; ks < 2; ++ks) {
            int slot = ((ks * 4 + quad) ^ sw) * 8;
            bf16x8 af[4], bfr[4];
#pragma unroll
            for (int i = 0; i < 4; ++i)
                af[i] = *(bf16x8*)(As + (wr + i * 16 + l16) * 64 + slot);
#pragma unroll
            for (int j = 0; j < 4; ++j)
                bfr[j] = *(bf16x8*)(Bs + (wc + j * 16 + l16) * 64 + slot);
#pragma unroll
            for (int i = 0; i < 4; ++i)
#pragma unroll
                for (int j = 0; j < 4; ++j)
                    acc[i][j] = mfma16(af[i], bfr[j], acc[i][j]);
        }
        __syncthreads();
    }

#pragma unroll
    for (int j = 0; j < 4; ++j) {
        int col = n0 + wc + j * 16 + l16;
#pragma unroll
        for (int i = 0; i < 4; ++i) {
#pragma unroll
            for (int r = 0; r < 4; ++r) {
                int row = m0 + wr + i * 16 + quad * 4 + r;
                atomicAdd(&Cf[(size_t)row * N + col], acc[i][j][r]);
            }
        }
    }
}

// ---------------------------------------------------------------------------
// Windowed attention with global column (structure unchanged since round 4).
// ---------------------------------------------------------------------------
__global__ __launch_bounds__(256, 2) void attn_kernel(
    const short* __restrict__ QKV, const short* __restrict__ Vt,
    const int* __restrict__ mask,
    const float* __restrict__ bk, const float* __restrict__ bv,
    short* __restrict__ attn)
{
    extern __shared__ char smem[];
    short* PsQ = (short*)smem;
    short* KV  = (short*)(smem + 34816);
    float* gkf = (float*)(smem + 53248);
    float* gvf = (float*)(smem + 53504);

    int blk = blockIdx.x;
    int c = blk & 15, h = (blk >> 4) & 15, b = blk >> 8;
    int t = threadIdx.x;
    int wave = t >> 6, lane = t & 63, quad = lane >> 4, l16 = lane & 15;
    int q0 = c * 128;
    const int bs_off = b * 2048;
    const short* Q = QKV + h * 64;
    const short* K = QKV + 1024 + h * 64;

#pragma unroll
    for (int l = 0; l < 4; ++l) {
        int idx = l * 256 + t;
        int p = idx >> 3, dc = (idx & 7) * 8;
        *(bf16x8*)(PsQ + p * 72 + dc) =
            *(const bf16x8*)(Q + ((size_t)(bs_off + q0 + p)) * 3072 + dc);
    }
    if (t < 64) { gkf[t] = bk[h * 64 + t]; gvf[t] = bv[h * 64 + t]; }
    __syncthreads();

    bf16x8 aq[2][2];
#pragma unroll
    for (int ti = 0; ti < 2; ++ti)
#pragma unroll
        for (int ks = 0; ks < 2; ++ks)
            aq[ti][ks] = *(bf16x8*)(PsQ + (wave * 32 + ti * 16 + l16) * 72 + ks * 32 + quad * 8);

    float s_g[2][4];
#pragma unroll
    for (int ti = 0; ti < 2; ++ti)
#pragma unroll
        for (int r = 0; r < 4; ++r) {
            int row = wave * 32 + ti * 16 + quad * 4 + r;
            float part = 0.f;
#pragma unroll
            for (int dd = 0; dd < 4; ++dd) {
                int d = l16 * 4 + dd;
                part += b2f(PsQ[row * 72 + d]) * gkf[d];
            }
#pragma unroll
            for (int dsh = 1; dsh < 16; dsh <<= 1) part += __shfl_xor(part, dsh);
            s_g[ti][r] = part;
        }

    f32x4 o_acc[2][4] = {};
    float m_run[2][4], l_run[2][4];
#pragma unroll
    for (int ti = 0; ti < 2; ++ti)
#pragma unroll
        for (int r = 0; r < 4; ++r) { m_run[ti][r] = NEGF; l_run[ti][r] = 0.f; }

    int kt_beg = (q0 == 0) ? 1 : 0;
    int kt_end = (q0 + 256 > 2048) ? 2 : 3;
    for (int kt = kt_beg; kt < kt_end; ++kt) {
        int jb = q0 + (kt - 1) * 128;
        __syncthreads();
#pragma unroll
        for (int l = 0; l < 4; ++l) {
            int idx = l * 256 + t;
            int p = idx >> 3, dc = (idx & 7) * 8;
            *(bf16x8*)(KV + p * 72 + dc) =
                *(const bf16x8*)(K + ((size_t)(bs_off + jb + p)) * 3072 + dc);
        }
        __syncthreads();

        f32x4 s_acc[2][8] = {};
#pragma unroll
        for (int ks = 0; ks < 2; ++ks) {
            bf16x8 bk8[8];
#pragma unroll
            for (int tj = 0; tj < 8; ++tj)
                bk8[tj] = *(bf16x8*)(KV + (tj * 16 + l16) * 72 + ks * 32 + quad * 8);
#pragma unroll
            for (int ti = 0; ti < 2; ++ti)
#pragma unroll
                for (int tj = 0; tj < 8; ++tj)
                    s_acc[ti][tj] = mfma16(aq[ti][ks], bk8[tj], s_acc[ti][tj]);
        }

        float negj[8]; int jcol[8];
#pragma unroll
        for (int tj = 0; tj < 8; ++tj) {
            jcol[tj] = jb + tj * 16 + l16;
            negj[tj] = (mask[bs_off + jcol[tj]] != 0) ? NEGF : 0.f;
        }
        float tmax[2][4];
#pragma unroll
        for (int ti = 0; ti < 2; ++ti)
#pragma unroll
            for (int r = 0; r < 4; ++r) tmax[ti][r] = NEGF;
#pragma unroll
        for (int ti = 0; ti < 2; ++ti) {
            int irow_base = q0 + wave * 32 + ti * 16 + quad * 4;
#pragma unroll
            for (int tj = 0; tj < 8; ++tj)
#pragma unroll
                for (int r = 0; r < 4; ++r) {
                    int dj = jcol[tj] - (irow_base + r);
                    float sc = (dj >= -128 && dj <= 128) ? (s_acc[ti][tj][r] + negj[tj]) : NEGF;
                    s_acc[ti][tj][r] = sc;
                    tmax[ti][r] = fmaxf(tmax[ti][r], sc);
                }
        }
#pragma unroll
        for (int ti = 0; ti < 2; ++ti)
#pragma unroll
            for (int r = 0; r < 4; ++r)
#pragma unroll
                for (int dsh = 1; dsh < 16; dsh <<= 1)
                    tmax[ti][r] = fmaxf(tmax[ti][r], __shfl_xor(tmax[ti][r], dsh));

        float alpha[2][4], lsum[2][4];
#pragma unroll
        for (int ti = 0; ti < 2; ++ti)
#pragma unroll
            for (int r = 0; r < 4; ++r) {
                float mnew = fmaxf(m_run[ti][r], tmax[ti][r]);
                alpha[ti][r] = safe_exp(m_run[ti][r] - mnew);
                m_run[ti][r] = mnew;
                lsum[ti][r] = 0.f;
            }
#pragma unroll
        for (int ti = 0; ti < 2; ++ti)
#pragma unroll
            for (int tj = 0; tj < 8; ++tj)
#pragma unroll
                for (int r = 0; r < 4; ++r) {
                    float p = safe_exp(s_acc[ti][tj][r] - m_run[ti][r]);
                    lsum[ti][r] += p;
                    PsQ[(wave * 32 + ti * 16 + quad * 4 + r) * 136 + tj * 16 + l16] = f2b(p);
                }
#pragma unroll
        for (int ti = 0; ti < 2; ++ti)
#pragma unroll
            for (int r = 0; r < 4; ++r) {
#pragma unroll
                for (int dsh = 1; dsh < 16; dsh <<= 1) lsum[ti][r] += __shfl_xor(lsum[ti][r], dsh);
                l_run[ti][r] = l_run[ti][r] * alpha[ti][r] + lsum[ti][r];
            }
#pragma unroll
        for (int ti = 0; ti < 2; ++ti)
#pragma unroll
            for (int dj = 0; dj < 4; ++dj)
#pragma unroll
                for (int r = 0; r < 4; ++r) o_acc[ti][dj][r] *= alpha[ti][r];

        __syncthreads();
#pragma unroll
        for (int l = 0; l < 4; ++l) {
            int idx = l * 256 + t;
            int d = idx >> 4, kc = (idx & 15) * 8;
            *(bf16x8*)(KV + d * 136 + kc) =
                *(const bf16x8*)(Vt + ((size_t)(b * 16 + h) * 64 + d) * 2048 + jb + kc);
        }
        __syncthreads();
#pragma unroll
        for (int ks = 0; ks < 4; ++ks) {
            bf16x8 ap[2], bv8[4];
#pragma unroll
            for (int ti = 0; ti < 2; ++ti)
                ap[ti] = *(bf16x8*)(PsQ + (wave * 32 + ti * 16 + l16) * 136 + ks * 32 + quad * 8);
#pragma unroll
            for (int dj = 0; dj < 4; ++dj)
                bv8[dj] = *(bf16x8*)(KV + (dj * 16 + l16) * 136 + ks * 32 + quad * 8);
#pragma unroll
            for (int ti = 0; ti < 2; ++ti)
#pragma unroll
                for (int dj = 0; dj < 4; ++dj)
                    o_acc[ti][dj] = mfma16(ap[ti], bv8[dj], o_acc[ti][dj]);
        }
    }

#pragma unroll
    for (int ti = 0; ti < 2; ++ti) {
        int irow_base = q0 + wave * 32 + ti * 16 + quad * 4;
#pragma unroll
        for (int r = 0; r < 4; ++r) {
            int i = irow_base + r;
            float m2 = fmaxf(m_run[ti][r], s_g[ti][r]);
            float pg = safe_exp(s_g[ti][r] - m2);
            float al = safe_exp(m_run[ti][r] - m2);
            float l2 = l_run[ti][r] * al + pg;
            float invl = 1.f / fmaxf(l2, 1e-30f);
            float qm = (mask[bs_off + i] > 0) ? 0.f : 1.f;
#pragma unroll
            for (int dj = 0; dj < 4; ++dj) {
                int d = dj * 16 + l16;
                float val = (o_acc[ti][dj][r] * al + pg * gvf[d]) * invl * qm;
                attn[((size_t)(bs_off + i)) * 1024 + h * 64 + d] = f2b(val);
            }
        }
    }
}

// ---------------------------------------------------------------------------
// y = LN(x + attn) * g + b ; writes bf16 (GEMM input), fp32 (residual),
// AND pre-fills out = y + b2 (split-K MLP2 atomically accumulates h@w2 on top)
// ---------------------------------------------------------------------------
__global__ __launch_bounds__(256) void resid_ln(
    const float* __restrict__ x, const short* __restrict__ attn,
    const float* __restrict__ g, const float* __restrict__ be,
    const float* __restrict__ b2,
    short* __restrict__ yb, float* __restrict__ yf, float* __restrict__ outp)
{
    int row = blockIdx.x, t = threadIdx.x;
    int lane = t & 63, wave = t >> 6;
    const size_t base = (size_t)row * 1024;
    float v[4]; float s = 0.f, s2 = 0.f;
#pragma unroll
    for (int i = 0; i < 4; ++i) {
        int c = i * 256 + t;
        float val = x[base + c] + b2f(attn[base + c]);
        v[i] = val; s += val; s2 += val * val;
    }
#pragma unroll
    for (int off = 32; off > 0; off >>= 1) { s += __shfl_xor(s, off); s2 += __shfl_xor(s2, off); }
    __shared__ float red[8];
    if (lane == 0) { red[wave] = s; red[4 + wave] = s2; }
    __syncthreads();
    s  = red[0] + red[1] + red[2] + red[3];
    s2 = red[4] + red[5] + red[6] + red[7];
    float mu  = s * (1.f / 1024.f);
    float var = s2 * (1.f / 1024.f) - mu * mu;
    float inv = rsqrtf(fmaxf(var, 0.f) + 1e-5f);
#pragma unroll
    for (int i = 0; i < 4; ++i) {
        int c = i * 256 + t;
        float o = (v[i] - mu) * inv * g[c] + be[c];
        yb[base + c] = f2b(o);
        yf[base + c] = o;
        outp[base + c] = o + b2[c];
    }
}

// ---------------------------------------------------------------------------
// workspace layout, units = bf16 elements (2 B). total 47M units = 94 MB.
// ---------------------------------------------------------------------------
static constexpr size_t MEG      = 1048576;
static constexpr size_t OFF_WQKV = 0;            // 3M  (3072x1024 bf16)
static constexpr size_t OFF_W1T  = 3 * MEG;      // 4M
static constexpr size_t OFF_W2T  = 7 * MEG;      // 4M
static constexpr size_t OFF_XB   = 11 * MEG;     // 4M
static constexpr size_t OFF_QKV  = 15 * MEG;     // 12M (4096x3072 bf16; V third unused)
static constexpr size_t OFF_VT   = 27 * MEG;     // 4M
static constexpr size_t OFF_ATT  = 31 * MEG;     // 4M
static constexpr size_t OFF_YN   = 35 * MEG;     // 4M (bf16)
static constexpr size_t OFF_YF   = 39 * MEG;     // 8M units = 4M fp32
static constexpr size_t OFF_H    = OFF_QKV;      // 16M, aliases QKV+VT (dead)

extern "C" void kernel_launch(void* const* d_in, const int* in_sizes, int n_in,
                              void* d_out, int out_size, void* d_ws, size_t ws_size,
                              hipStream_t stream) {
    (void)in_sizes; (void)n_in; (void)out_size; (void)ws_size;
    const float* x    = (const float*)d_in[0];
    const int*   mask = (const int*)  d_in[1];
    const float* wq   = (const float*)d_in[2];
    const float* bq   = (const float*)d_in[3];
    const float* wk   = (const float*)d_in[4];
    const float* bk   = (const float*)d_in[5];
    const float* wv   = (const float*)d_in[6];
    const float* bv   = (const float*)d_in[7];
    // d_in[8..13] (global-query branch) are provably dead for the output
    const float* lng  = (const float*)d_in[14];
    const float* lnb  = (const float*)d_in[15];
    const float* w1   = (const float*)d_in[16];
    const float* b1   = (const float*)d_in[17];
    const float* w2   = (const float*)d_in[18];
    const float* b2   = (const float*)d_in[19];
    short* ws  = (short*)d_ws;
    float* out = (float*)d_out;

    dim3 tb(32, 8);
    cvt_transpose_qkv<<<dim3(32, 32, 3), tb, 0, stream>>>(wq, wk, wv, ws + OFF_WQKV);
    cvt_transpose<<<dim3(128, 32), tb, 0, stream>>>(w1, ws + OFF_W1T, 1024, 4096);
    cvt_transpose<<<dim3(32, 128), tb, 0, stream>>>(w2, ws + OFF_W2T, 4096, 1024);
    cvt_f32_bf16<<<4096, 256, 0, stream>>>(x, ws + OFF_XB, 4194304);

    // QKV = x @ [wq|wk|wv] + [bq|bk|bv]; Q scaled 1/8; V written to Vt fused
    gemm_bt<<<dim3(32, 24), 256, 0, stream>>>(ws + OFF_XB, ws + OFF_WQKV,
                                              bq, bk, bv,
                                              ws + OFF_QKV, ws + OFF_VT,
                                              4096, 3072, 1024, 0.125f, 0);

    attn_kernel<<<512, 256, 53760, stream>>>(ws + OFF_QKV, ws + OFF_VT,
                                             mask, bk, bv, ws + OFF_ATT);

    // y = LN(x+attn); also pre-fills out = y + b2 for the split-K MLP2
    resid_ln<<<4096, 256, 0, stream>>>(x, ws + OFF_ATT, lng, lnb, b2,
                                       ws + OFF_YN, (float*)(ws + OFF_YF), out);

    // h = gelu(y@w1 + b1)
    gemm_bt<<<dim3(32, 32), 256, 0, stream>>>(ws + OFF_YN, ws + OFF_W1T,
                                              b1, nullptr, nullptr,
                                              ws + OFF_H, nullptr,
                                              4096, 4096, 1024, 1.0f, 1);
    // out += h@w2 (split-K x4, atomic fp32 accumulate; out pre-filled y+b2)
    gemm128_sk<<<dim3(32, 8, 4), 256, 0, stream>>>(ws + OFF_H, ws + OFF_W2T,
                                                   out, 4096, 1024, 4096, 1024);
}

// Round 4
// 354.110 us; speedup vs baseline: 1.0293x; 1.0293x over previous
//
#include <hip/hip_runtime.h>

// ---------------------------------------------------------------------------
// HFLongFormerSelfAttentionBlock — MI355X implementation (round 10)
//
// I/O fp32; internal bf16 MFMA, fp32 accumulation/epilogues.
// Round-10:
//  * MLP2: split-K atomics removed (rocprof: WRITE 64 MB = 4x amplification,
//    74us > round-0's 57us). Back to the 64^2-tile 4-block/CU structure, now
//    with 2-deep double-buffered LDS + counted s_waitcnt vmcnt(4) (loads stay
//    in flight across barriers; occupancy preserved, unlike round 7).
//  * QKV Vt epilogue: was 8-B stores at 4KB stride (write amplification);
//    now staged transposed in LDS, 16-B coalesced stores along s.
//  * resid_ln: no out prefill (gemm64_db reads resf).
// ---------------------------------------------------------------------------

using bf16x8 = __attribute__((ext_vector_type(8))) short;
using bf16x4 = __attribute__((ext_vector_type(4))) short;
using f32x4  = __attribute__((ext_vector_type(4))) float;

__device__ __forceinline__ float b2f(short s) {
    return __uint_as_float(((unsigned int)(unsigned short)s) << 16);
}
__device__ __forceinline__ short f2b(float f) {
    unsigned int u = __float_as_uint(f);
    u += 0x7fffu + ((u >> 16) & 1u);   // round-to-nearest-even
    return (short)(u >> 16);
}
__device__ __forceinline__ f32x4 mfma16(bf16x8 a, bf16x8 b, f32x4 c) {
    return __builtin_amdgcn_mfma_f32_16x16x32_bf16(a, b, c, 0, 0, 0);
}
__device__ __forceinline__ float safe_exp(float x) {
    return expf((x <= 0.f) ? x : 0.f);
}
// async global->LDS, 16 B per lane; LDS dest = wave-uniform base + lane*16
__device__ __forceinline__ void load_lds16(const short* g, short* l) {
    __builtin_amdgcn_global_load_lds((const __attribute__((address_space(1))) void*)g,
                                     (__attribute__((address_space(3))) void*)l, 16, 0, 0);
}
#define NEGF (-3.0e38f)

// ---------------------------------------------------------------------------
// fp32 -> bf16 elementwise convert (n multiple of 1024). grid n/1024, 256 thr
// ---------------------------------------------------------------------------
__global__ void cvt_f32_bf16(const float* __restrict__ in, short* __restrict__ out, int n) {
    int i = (blockIdx.x * 256 + threadIdx.x) * 4;
    f32x4 v = *(const f32x4*)(in + i);
    bf16x4 o;
#pragma unroll
    for (int j = 0; j < 4; ++j) o[j] = f2b(v[j]);
    *(bf16x4*)(out + i) = o;
}

// ---------------------------------------------------------------------------
// fp32 in, bf16 transposed out: out[c][r] = in[r][c], in is R x C.
// grid (C/32, R/32), block (32,8)
// ---------------------------------------------------------------------------
__global__ void cvt_transpose(const float* __restrict__ in, short* __restrict__ out,
                              int R, int C) {
    __shared__ short tile[32][33];
    int bx = blockIdx.x * 32, by = blockIdx.y * 32;
    int tx = threadIdx.x, ty = threadIdx.y;
    for (int i = ty; i < 32; i += 8)
        tile[i][tx] = f2b(in[(size_t)(by + i) * C + bx + tx]);
    __syncthreads();
    for (int i = ty; i < 32; i += 8)
        out[(size_t)(bx + i) * R + by + tx] = tile[tx][i];
}

// wq/wk/wv (each 1024x1024 fp32) -> WQKVT (3072x1024 bf16, = [wq^T;wk^T;wv^T])
__global__ void cvt_transpose_qkv(const float* __restrict__ wq, const float* __restrict__ wk,
                                  const float* __restrict__ wv, short* __restrict__ out) {
    __shared__ short tile[32][33];
    const float* in = (blockIdx.z == 0) ? wq : (blockIdx.z == 1) ? wk : wv;
    short* dst = out + (size_t)blockIdx.z * 1024 * 1024;
    int bx = blockIdx.x * 32, by = blockIdx.y * 32;
    int tx = threadIdx.x, ty = threadIdx.y;
    for (int i = ty; i < 32; i += 8)
        tile[i][tx] = f2b(in[(size_t)(by + i) * 1024 + bx + tx]);
    __syncthreads();
    for (int i = ty; i < 32; i += 8)
        dst[(size_t)(bx + i) * 1024 + by + tx] = tile[tx][i];
}

// ---------------------------------------------------------------------------
// GEMM 128x128, BK=64, XOR-swizzled LDS k-chunks.
// mode 0: QKV — bias by col segment, Q scaled, V staged+transposed -> Vt
// mode 1: C = bf16(gelu(acc + bias0[col]))
// Epilogue always stages the tile in LDS, then coalesced 16-B stores.
// ---------------------------------------------------------------------------
__global__ __launch_bounds__(256, 3) void gemm_bt(
    const short* __restrict__ A, const short* __restrict__ Bt,
    const float* __restrict__ bias0, const float* __restrict__ bias1,
    const float* __restrict__ bias2,
    short* __restrict__ C, short* __restrict__ Vt,
    int M, int N, int K, float scale, int mode)
{
    __shared__ short sh[128 * 136];   // 34.8 KB; main loop uses first 16K shorts
    short* As = sh;
    short* Bs = sh + 8192;
    int m0 = blockIdx.x * 128, n0 = blockIdx.y * 128;
    int t = threadIdx.x;
    int wave = t >> 6, lane = t & 63, quad = lane >> 4, l16 = lane & 15;
    int wr = (wave >> 1) * 64, wc = (wave & 1) * 64;

    // staging pointers: 4 chunks per wave per buffer
    const short* ap[4]; const short* bp[4]; short* la[4]; short* lb[4];
    int gk = (((lane & 7) ^ (lane >> 3)) * 8);
#pragma unroll
    for (int l = 0; l < 4; ++l) {
        int c = wave * 4 + l;
        int row = c * 8 + (lane >> 3);
        ap[l] = A  + (size_t)(m0 + row) * K + gk;
        bp[l] = Bt + (size_t)(n0 + row) * K + gk;
        la[l] = As + c * 512;
        lb[l] = Bs + c * 512;
    }
    int sw = l16 & 7;   // frag-read swizzle key

    f32x4 acc[4][4] = {};
    for (int k0 = 0; k0 < K; k0 += 64) {
#pragma unroll
        for (int l = 0; l < 4; ++l) { load_lds16(ap[l] + k0, la[l]); load_lds16(bp[l] + k0, lb[l]); }
        __syncthreads();
#pragma unroll
        for (int ks = 0; ks < 2; ++ks) {
            int slot = ((ks * 4 + quad) ^ sw) * 8;
            bf16x8 af[4], bfr[4];
#pragma unroll
            for (int i = 0; i < 4; ++i)
                af[i] = *(bf16x8*)(As + (wr + i * 16 + l16) * 64 + slot);
#pragma unroll
            for (int j = 0; j < 4; ++j)
                bfr[j] = *(bf16x8*)(Bs + (wc + j * 16 + l16) * 64 + slot);
#pragma unroll
            for (int i = 0; i < 4; ++i)
#pragma unroll
                for (int j = 0; j < 4; ++j)
                    acc[i][j] = mfma16(af[i], bfr[j], acc[i][j]);
        }
        __syncthreads();
    }
    // after final barrier, all LDS reads are done -> sh reusable for staging

    int seg0 = n0 >> 10;   // tiles are 128-aligned: never straddle a segment
    if (mode == 1 || seg0 < 2) {
        // ---- stage bf16 tile in LDS: sh[row*136 + col], row/col in [0,128)
        if (mode == 1) {
#pragma unroll
            for (int j = 0; j < 4; ++j) {
                int col = n0 + wc + j * 16 + l16;
                float bs = bias0[col];
#pragma unroll
                for (int i = 0; i < 4; ++i)
#pragma unroll
                    for (int r = 0; r < 4; ++r) {
                        float v = acc[i][j][r] + bs;
                        v = 0.5f * v * (1.0f + erff(v * 0.70710678118f));
                        sh[(wr + i * 16 + quad * 4 + r) * 136 + wc + j * 16 + l16] = f2b(v);
                    }
            }
        } else {
            float sc = (seg0 == 0) ? scale : 1.0f;
            const float* bpt = (seg0 == 0) ? bias0 : bias1;
#pragma unroll
            for (int j = 0; j < 4; ++j) {
                int col = n0 + wc + j * 16 + l16;
                float bs = bpt[col & 1023];
#pragma unroll
                for (int i = 0; i < 4; ++i)
#pragma unroll
                    for (int r = 0; r < 4; ++r)
                        sh[(wr + i * 16 + quad * 4 + r) * 136 + wc + j * 16 + l16] =
                            f2b((acc[i][j][r] + bs) * sc);
            }
        }
        __syncthreads();
        // ---- coalesced write-out: 2 threads per row, 8 x 16 B each
        int row = t >> 1, half = t & 1;
        const short* src = sh + row * 136 + half * 64;
        short* dst = C + (size_t)(m0 + row) * N + n0 + half * 64;
#pragma unroll
        for (int cgk = 0; cgk < 8; ++cgk)
            *(bf16x8*)(dst + cgk * 8) = *(const bf16x8*)(src + cgk * 8);
    } else {
        // ---- V part: stage TRANSPOSED in LDS (sh[c*136 + row]), then write
        //      Vt (b, h, d, s) with 16-B chunks coalesced along s.
#pragma unroll
        for (int j = 0; j < 4; ++j) {
            int cl = wc + j * 16 + l16;                 // local col in [0,128)
            float bs = bias2[(n0 & 1023) + cl];
#pragma unroll
            for (int i = 0; i < 4; ++i)
#pragma unroll
                for (int r = 0; r < 4; ++r)
                    sh[cl * 136 + wr + i * 16 + quad * 4 + r] = f2b(acc[i][j][r] + bs);
        }
        __syncthreads();
        int h0 = (n0 & 1023) >> 6;                      // first head of tile
        int bb = m0 >> 11, s0 = m0 & 2047;
        int sc = t & 15;                                // s-chunk within tile
#pragma unroll
        for (int cgk = 0; cgk < 8; ++cgk) {
            int cl = (t >> 4) + cgk * 16;               // local col
            int h = h0 + (cl >> 6), d = cl & 63;
            *(bf16x8*)(Vt + (((size_t)(bb * 16 + h)) * 64 + d) * 2048 + s0 + sc * 8) =
                *(const bf16x8*)(sh + cl * 136 + sc * 8);
        }
    }
}

// ---------------------------------------------------------------------------
// GEMM 64x64, BK=64, XOR swizzle, DOUBLE-buffered LDS with counted vmcnt(4):
// tile t+1's 4 loads are issued before computing tile t and stay in flight
// across the barrier (never drained to 0 mid-loop). LDS 32 KB -> still
// 4 blocks/CU, so TLP is preserved (round-7 lesson) AND latency is hidden.
// Cf = A@B + bias + resf (fp32 out). grid (M/64, N/64), 256 thr.
// ---------------------------------------------------------------------------
__global__ __launch_bounds__(256, 4) void gemm64_db(
    const short* __restrict__ A, const short* __restrict__ Bt,
    const float* __restrict__ bias, const float* __restrict__ resf,
    float* __restrict__ Cf, int M, int N, int K)
{
    __shared__ short As[2][64 * 64];
    __shared__ short Bs[2][64 * 64];
    int m0 = blockIdx.x * 64, n0 = blockIdx.y * 64;
    int t = threadIdx.x;
    int wave = t >> 6, lane = t & 63, quad = lane >> 4, l16 = lane & 15;
    int wr = (wave >> 1) * 32, wc = (wave & 1) * 32;

    const short* ap[2]; const short* bp[2]; int lo[2];
    int gk = (((lane & 7) ^ (lane >> 3)) * 8);
#pragma unroll
    for (int l = 0; l < 2; ++l) {
        int c = wave * 2 + l;
        int row = c * 8 + (lane >> 3);
        ap[l] = A  + (size_t)(m0 + row) * K + gk;
        bp[l] = Bt + (size_t)(n0 + row) * K + gk;
        lo[l] = c * 512;
    }
    int sw = l16 & 7;

    const int nt = K >> 6;
    // prologue: stage tile 0 into buffer 0
#pragma unroll
    for (int l = 0; l < 2; ++l) { load_lds16(ap[l], &As[0][lo[l]]); load_lds16(bp[l], &Bs[0][lo[l]]); }

    f32x4 acc[2][2] = {};
    for (int ti = 0; ti < nt; ++ti) {
        int cur = ti & 1;
        if (ti + 1 < nt) {
            int k0 = (ti + 1) << 6;
#pragma unroll
            for (int l = 0; l < 2; ++l) {
                load_lds16(ap[l] + k0, &As[cur ^ 1][lo[l]]);
                load_lds16(bp[l] + k0, &Bs[cur ^ 1][lo[l]]);
            }
            asm volatile("s_waitcnt vmcnt(4)" ::: "memory");  // wait cur's loads only
        } else {
            asm volatile("s_waitcnt vmcnt(0)" ::: "memory");
        }
        __builtin_amdgcn_s_barrier();
        asm volatile("" ::: "memory");

        const short* as = &As[cur][0];
        const short* bs = &Bs[cur][0];
#pragma unroll
        for (int ks = 0; ks < 2; ++ks) {
            int slot = ((ks * 4 + quad) ^ sw) * 8;
            bf16x8 af[2], bfr[2];
#pragma unroll
            for (int i = 0; i < 2; ++i)
                af[i] = *(bf16x8*)(as + (wr + i * 16 + l16) * 64 + slot);
#pragma unroll
            for (int j = 0; j < 2; ++j)
                bfr[j] = *(bf16x8*)(bs + (wc + j * 16 + l16) * 64 + slot);
#pragma unroll
            for (int i = 0; i < 2; ++i)
#pragma unroll
                for (int j = 0; j < 2; ++j)
                    acc[i][j] = mfma16(af[i], bfr[j], acc[i][j]);
        }
        asm volatile("" ::: "memory");
        __builtin_amdgcn_s_barrier();   // protect buf cur^1 before next stage
    }

#pragma unroll
    for (int j = 0; j < 2; ++j) {
        int col = n0 + wc + j * 16 + l16;
        float bs = bias[col];
#pragma unroll
        for (int i = 0; i < 2; ++i) {
#pragma unroll
            for (int r = 0; r < 4; ++r) {
                int row = m0 + wr + i * 16 + quad * 4 + r;
                Cf[(size_t)row * N + col] = acc[i][j][r] + bs + resf[(size_t)row * N + col];
            }
        }
    }
}

// ---------------------------------------------------------------------------
// Windowed attention with global column (structure unchanged since round 4).
// ---------------------------------------------------------------------------
__global__ __launch_bounds__(256, 2) void attn_kernel(
    const short* __restrict__ QKV, const short* __restrict__ Vt,
    const int* __restrict__ mask,
    const float* __restrict__ bk, const float* __restrict__ bv,
    short* __restrict__ attn)
{
    extern __shared__ char smem[];
    short* PsQ = (short*)smem;
    short* KV  = (short*)(smem + 34816);
    float* gkf = (float*)(smem + 53248);
    float* gvf = (float*)(smem + 53504);

    int blk = blockIdx.x;
    int c = blk & 15, h = (blk >> 4) & 15, b = blk >> 8;
    int t = threadIdx.x;
    int wave = t >> 6, lane = t & 63, quad = lane >> 4, l16 = lane & 15;
    int q0 = c * 128;
    const int bs_off = b * 2048;
    const short* Q = QKV + h * 64;
    const short* K = QKV + 1024 + h * 64;

#pragma unroll
    for (int l = 0; l < 4; ++l) {
        int idx = l * 256 + t;
        int p = idx >> 3, dc = (idx & 7) * 8;
        *(bf16x8*)(PsQ + p * 72 + dc) =
            *(const bf16x8*)(Q + ((size_t)(bs_off + q0 + p)) * 3072 + dc);
    }
    if (t < 64) { gkf[t] = bk[h * 64 + t]; gvf[t] = bv[h * 64 + t]; }
    __syncthreads();

    bf16x8 aq[2][2];
#pragma unroll
    for (int ti = 0; ti < 2; ++ti)
#pragma unroll
        for (int ks = 0; ks < 2; ++ks)
            aq[ti][ks] = *(bf16x8*)(PsQ + (wave * 32 + ti * 16 + l16) * 72 + ks * 32 + quad * 8);

    float s_g[2][4];
#pragma unroll
    for (int ti = 0; ti < 2; ++ti)
#pragma unroll
        for (int r = 0; r < 4; ++r) {
            int row = wave * 32 + ti * 16 + quad * 4 + r;
            float part = 0.f;
#pragma unroll
            for (int dd = 0; dd < 4; ++dd) {
                int d = l16 * 4 + dd;
                part += b2f(PsQ[row * 72 + d]) * gkf[d];
            }
#pragma unroll
            for (int dsh = 1; dsh < 16; dsh <<= 1) part += __shfl_xor(part, dsh);
            s_g[ti][r] = part;
        }

    f32x4 o_acc[2][4] = {};
    float m_run[2][4], l_run[2][4];
#pragma unroll
    for (int ti = 0; ti < 2; ++ti)
#pragma unroll
        for (int r = 0; r < 4; ++r) { m_run[ti][r] = NEGF; l_run[ti][r] = 0.f; }

    int kt_beg = (q0 == 0) ? 1 : 0;
    int kt_end = (q0 + 256 > 2048) ? 2 : 3;
    for (int kt = kt_beg; kt < kt_end; ++kt) {
        int jb = q0 + (kt - 1) * 128;
        __syncthreads();
#pragma unroll
        for (int l = 0; l < 4; ++l) {
            int idx = l * 256 + t;
            int p = idx >> 3, dc = (idx & 7) * 8;
            *(bf16x8*)(KV + p * 72 + dc) =
                *(const bf16x8*)(K + ((size_t)(bs_off + jb + p)) * 3072 + dc);
        }
        __syncthreads();

        f32x4 s_acc[2][8] = {};
#pragma unroll
        for (int ks = 0; ks < 2; ++ks) {
            bf16x8 bk8[8];
#pragma unroll
            for (int tj = 0; tj < 8; ++tj)
                bk8[tj] = *(bf16x8*)(KV + (tj * 16 + l16) * 72 + ks * 32 + quad * 8);
#pragma unroll
            for (int ti = 0; ti < 2; ++ti)
#pragma unroll
                for (int tj = 0; tj < 8; ++tj)
                    s_acc[ti][tj] = mfma16(aq[ti][ks], bk8[tj], s_acc[ti][tj]);
        }

        float negj[8]; int jcol[8];
#pragma unroll
        for (int tj = 0; tj < 8; ++tj) {
            jcol[tj] = jb + tj * 16 + l16;
            negj[tj] = (mask[bs_off + jcol[tj]] != 0) ? NEGF : 0.f;
        }
        float tmax[2][4];
#pragma unroll
        for (int ti = 0; ti < 2; ++ti)
#pragma unroll
            for (int r = 0; r < 4; ++r) tmax[ti][r] = NEGF;
#pragma unroll
        for (int ti = 0; ti < 2; ++ti) {
            int irow_base = q0 + wave * 32 + ti * 16 + quad * 4;
#pragma unroll
            for (int tj = 0; tj < 8; ++tj)
#pragma unroll
                for (int r = 0; r < 4; ++r) {
                    int dj = jcol[tj] - (irow_base + r);
                    float sc = (dj >= -128 && dj <= 128) ? (s_acc[ti][tj][r] + negj[tj]) : NEGF;
                    s_acc[ti][tj][r] = sc;
                    tmax[ti][r] = fmaxf(tmax[ti][r], sc);
                }
        }
#pragma unroll
        for (int ti = 0; ti < 2; ++ti)
#pragma unroll
            for (int r = 0; r < 4; ++r)
#pragma unroll
                for (int dsh = 1; dsh < 16; dsh <<= 1)
                    tmax[ti][r] = fmaxf(tmax[ti][r], __shfl_xor(tmax[ti][r], dsh));

        float alpha[2][4], lsum[2][4];
#pragma unroll
        for (int ti = 0; ti < 2; ++ti)
#pragma unroll
            for (int r = 0; r < 4; ++r) {
                float mnew = fmaxf(m_run[ti][r], tmax[ti][r]);
                alpha[ti][r] = safe_exp(m_run[ti][r] - mnew);
                m_run[ti][r] = mnew;
                lsum[ti][r] = 0.f;
            }
#pragma unroll
        for (int ti = 0; ti < 2; ++ti)
#pragma unroll
            for (int tj = 0; tj < 8; ++tj)
#pragma unroll
                for (int r = 0; r < 4; ++r) {
                    float p = safe_exp(s_acc[ti][tj][r] - m_run[ti][r]);
                    lsum[ti][r] += p;
                    PsQ[(wave * 32 + ti * 16 + quad * 4 + r) * 136 + tj * 16 + l16] = f2b(p);
                }
#pragma unroll
        for (int ti = 0; ti < 2; ++ti)
#pragma unroll
            for (int r = 0; r < 4; ++r) {
#pragma unroll
                for (int dsh = 1; dsh < 16; dsh <<= 1) lsum[ti][r] += __shfl_xor(lsum[ti][r], dsh);
                l_run[ti][r] = l_run[ti][r] * alpha[ti][r] + lsum[ti][r];
            }
#pragma unroll
        for (int ti = 0; ti < 2; ++ti)
#pragma unroll
            for (int dj = 0; dj < 4; ++dj)
#pragma unroll
                for (int r = 0; r < 4; ++r) o_acc[ti][dj][r] *= alpha[ti][r];

        __syncthreads();
#pragma unroll
        for (int l = 0; l < 4; ++l) {
            int idx = l * 256 + t;
            int d = idx >> 4, kc = (idx & 15) * 8;
            *(bf16x8*)(KV + d * 136 + kc) =
                *(const bf16x8*)(Vt + ((size_t)(b * 16 + h) * 64 + d) * 2048 + jb + kc);
        }
        __syncthreads();
#pragma unroll
        for (int ks = 0; ks < 4; ++ks) {
            bf16x8 ap[2], bv8[4];
#pragma unroll
            for (int ti = 0; ti < 2; ++ti)
                ap[ti] = *(bf16x8*)(PsQ + (wave * 32 + ti * 16 + l16) * 136 + ks * 32 + quad * 8);
#pragma unroll
            for (int dj = 0; dj < 4; ++dj)
                bv8[dj] = *(bf16x8*)(KV + (dj * 16 + l16) * 136 + ks * 32 + quad * 8);
#pragma unroll
            for (int ti = 0; ti < 2; ++ti)
#pragma unroll
                for (int dj = 0; dj < 4; ++dj)
                    o_acc[ti][dj] = mfma16(ap[ti], bv8[dj], o_acc[ti][dj]);
        }
    }

#pragma unroll
    for (int ti = 0; ti < 2; ++ti) {
        int irow_base = q0 + wave * 32 + ti * 16 + quad * 4;
#pragma unroll
        for (int r = 0; r < 4; ++r) {
            int i = irow_base + r;
            float m2 = fmaxf(m_run[ti][r], s_g[ti][r]);
            float pg = safe_exp(s_g[ti][r] - m2);
            float al = safe_exp(m_run[ti][r] - m2);
            float l2 = l_run[ti][r] * al + pg;
            float invl = 1.f / fmaxf(l2, 1e-30f);
            float qm = (mask[bs_off + i] > 0) ? 0.f : 1.f;
#pragma unroll
            for (int dj = 0; dj < 4; ++dj) {
                int d = dj * 16 + l16;
                float val = (o_acc[ti][dj][r] * al + pg * gvf[d]) * invl * qm;
                attn[((size_t)(bs_off + i)) * 1024 + h * 64 + d] = f2b(val);
            }
        }
    }
}

// ---------------------------------------------------------------------------
// y = LN(x + attn) * g + b ; writes bf16 (GEMM input) AND fp32 (residual).
// ---------------------------------------------------------------------------
__global__ __launch_bounds__(256) void resid_ln(
    const float* __restrict__ x, const short* __restrict__ attn,
    const float* __restrict__ g, const float* __restrict__ be,
    short* __restrict__ yb, float* __restrict__ yf)
{
    int row = blockIdx.x, t = threadIdx.x;
    int lane = t & 63, wave = t >> 6;
    const size_t base = (size_t)row * 1024;
    float v[4]; float s = 0.f, s2 = 0.f;
#pragma unroll
    for (int i = 0; i < 4; ++i) {
        int c = i * 256 + t;
        float val = x[base + c] + b2f(attn[base + c]);
        v[i] = val; s += val; s2 += val * val;
    }
#pragma unroll
    for (int off = 32; off > 0; off >>= 1) { s += __shfl_xor(s, off); s2 += __shfl_xor(s2, off); }
    __shared__ float red[8];
    if (lane == 0) { red[wave] = s; red[4 + wave] = s2; }
    __syncthreads();
    s  = red[0] + red[1] + red[2] + red[3];
    s2 = red[4] + red[5] + red[6] + red[7];
    float mu  = s * (1.f / 1024.f);
    float var = s2 * (1.f / 1024.f) - mu * mu;
    float inv = rsqrtf(fmaxf(var, 0.f) + 1e-5f);
#pragma unroll
    for (int i = 0; i < 4; ++i) {
        int c = i * 256 + t;
        float o = (v[i] - mu) * inv * g[c] + be[c];
        yb[base + c] = f2b(o);
        yf[base + c] = o;
    }
}

// ---------------------------------------------------------------------------
// workspace layout, units = bf16 elements (2 B). total 47M units = 94 MB.
// ---------------------------------------------------------------------------
static constexpr size_t MEG      = 1048576;
static constexpr size_t OFF_WQKV = 0;            // 3M  (3072x1024 bf16)
static constexpr size_t OFF_W1T  = 3 * MEG;      // 4M
static constexpr size_t OFF_W2T  = 7 * MEG;      // 4M
static constexpr size_t OFF_XB   = 11 * MEG;     // 4M
static constexpr size_t OFF_QKV  = 15 * MEG;     // 12M (4096x3072 bf16; V third unused)
static constexpr size_t OFF_VT   = 27 * MEG;     // 4M
static constexpr size_t OFF_ATT  = 31 * MEG;     // 4M
static constexpr size_t OFF_YN   = 35 * MEG;     // 4M (bf16)
static constexpr size_t OFF_YF   = 39 * MEG;     // 8M units = 4M fp32
static constexpr size_t OFF_H    = OFF_QKV;      // 16M, aliases QKV+VT (dead)

extern "C" void kernel_launch(void* const* d_in, const int* in_sizes, int n_in,
                              void* d_out, int out_size, void* d_ws, size_t ws_size,
                              hipStream_t stream) {
    (void)in_sizes; (void)n_in; (void)out_size; (void)ws_size;
    const float* x    = (const float*)d_in[0];
    const int*   mask = (const int*)  d_in[1];
    const float* wq   = (const float*)d_in[2];
    const float* bq   = (const float*)d_in[3];
    const float* wk   = (const float*)d_in[4];
    const float* bk   = (const float*)d_in[5];
    const float* wv   = (const float*)d_in[6];
    const float* bv   = (const float*)d_in[7];
    // d_in[8..13] (global-query branch) are provably dead for the output
    const float* lng  = (const float*)d_in[14];
    const float* lnb  = (const float*)d_in[15];
    const float* w1   = (const float*)d_in[16];
    const float* b1   = (const float*)d_in[17];
    const float* w2   = (const float*)d_in[18];
    const float* b2   = (const float*)d_in[19];
    short* ws  = (short*)d_ws;
    float* out = (float*)d_out;

    dim3 tb(32, 8);
    cvt_transpose_qkv<<<dim3(32, 32, 3), tb, 0, stream>>>(wq, wk, wv, ws + OFF_WQKV);
    cvt_transpose<<<dim3(128, 32), tb, 0, stream>>>(w1, ws + OFF_W1T, 1024, 4096);
    cvt_transpose<<<dim3(32, 128), tb, 0, stream>>>(w2, ws + OFF_W2T, 4096, 1024);
    cvt_f32_bf16<<<4096, 256, 0, stream>>>(x, ws + OFF_XB, 4194304);

    // QKV = x @ [wq|wk|wv] + [bq|bk|bv]; Q scaled 1/8; V staged -> Vt fused
    gemm_bt<<<dim3(32, 24), 256, 0, stream>>>(ws + OFF_XB, ws + OFF_WQKV,
                                              bq, bk, bv,
                                              ws + OFF_QKV, ws + OFF_VT,
                                              4096, 3072, 1024, 0.125f, 0);

    attn_kernel<<<512, 256, 53760, stream>>>(ws + OFF_QKV, ws + OFF_VT,
                                             mask, bk, bv, ws + OFF_ATT);

    resid_ln<<<4096, 256, 0, stream>>>(x, ws + OFF_ATT, lng, lnb,
                                       ws + OFF_YN, (float*)(ws + OFF_YF));

    // h = gelu(y@w1 + b1)
    gemm_bt<<<dim3(32, 32), 256, 0, stream>>>(ws + OFF_YN, ws + OFF_W1T,
                                              b1, nullptr, nullptr,
                                              ws + OFF_H, nullptr,
                                              4096, 4096, 1024, 1.0f, 1);
    // out = y + h@w2 + b2 (64^2 tile, double-buffered, counted vmcnt)
    gemm64_db<<<dim3(64, 16), 256, 0, stream>>>(ws + OFF_H, ws + OFF_W2T,
                                                b2, (const float*)(ws + OFF_YF),
                                                out, 4096, 1024, 4096);
}

// Round 5
// 340.503 us; speedup vs baseline: 1.0704x; 1.0400x over previous
//
#include <hip/hip_runtime.h>

// ---------------------------------------------------------------------------
// HFLongFormerSelfAttentionBlock — MI355X implementation (round 11)
//
// I/O fp32; internal bf16 MFMA, fp32 accumulation/epilogues.
// Round-11 (three independent fixes, attributable via counters):
//  1. MLP1 gelu: libm erff (~35 divergent VALU ops x64/thread; rocprof showed
//     VALUBusy 26% on a 94us dispatch) -> branch-free A&S 7.1.25 fast erf
//     (~12 ops, v_rcp+v_exp, abs err 2.5e-5 << bf16 quantization).
//  2. gemm_bt occupancy 3 -> 4 blocks/CU (LDS 34.8KB*4 = 139 < 160 KB).
//  3. XCD-aware bijective block swizzle on gemm_bt / gemm64_db grids
//     (consecutive blocks within an XCD share the B-panel -> L2 locality).
// ---------------------------------------------------------------------------

using bf16x8 = __attribute__((ext_vector_type(8))) short;
using bf16x4 = __attribute__((ext_vector_type(4))) short;
using f32x4  = __attribute__((ext_vector_type(4))) float;

__device__ __forceinline__ float b2f(short s) {
    return __uint_as_float(((unsigned int)(unsigned short)s) << 16);
}
__device__ __forceinline__ short f2b(float f) {
    unsigned int u = __float_as_uint(f);
    u += 0x7fffu + ((u >> 16) & 1u);   // round-to-nearest-even
    return (short)(u >> 16);
}
__device__ __forceinline__ f32x4 mfma16(bf16x8 a, bf16x8 b, f32x4 c) {
    return __builtin_amdgcn_mfma_f32_16x16x32_bf16(a, b, c, 0, 0, 0);
}
__device__ __forceinline__ float safe_exp(float x) {
    return expf((x <= 0.f) ? x : 0.f);
}
// gelu(v) = 0.5 v (1 + erf(v/sqrt2)); erf via A&S 7.1.25 (|err| <= 2.5e-5,
// branch-free: rcp + exp + 5 fma). 100x below bf16 output quantization.
__device__ __forceinline__ float fast_gelu(float v) {
    float z  = fabsf(v) * 0.70710678118f;
    float t  = __builtin_amdgcn_rcpf(fmaf(0.47047f, z, 1.f));
    float e  = __expf(-z * z);
    float p  = t * fmaf(t, fmaf(t, 0.7478556f, -0.0958798f), 0.3480242f);
    float er = fmaf(-p, e, 1.f);                  // erf(|z|)
    er = (v < 0.f) ? -er : er;
    return 0.5f * v * (1.f + er);
}
// async global->LDS, 16 B per lane; LDS dest = wave-uniform base + lane*16
__device__ __forceinline__ void load_lds16(const short* g, short* l) {
    __builtin_amdgcn_global_load_lds((const __attribute__((address_space(1))) void*)g,
                                     (__attribute__((address_space(3))) void*)l, 16, 0, 0);
}
// XCD-aware bijective swizzle of the flat block id (grids here are %8==0).
// Consecutive remapped ids land on the same XCD and walk m fastest.
__device__ __forceinline__ int xcd_swizzle_flat() {
    int fid = blockIdx.x + blockIdx.y * gridDim.x;
    int nwg = gridDim.x * gridDim.y;
    return (fid & 7) * (nwg >> 3) + (fid >> 3);
}
#define NEGF (-3.0e38f)

// ---------------------------------------------------------------------------
// fp32 -> bf16 elementwise convert (n multiple of 1024). grid n/1024, 256 thr
// ---------------------------------------------------------------------------
__global__ void cvt_f32_bf16(const float* __restrict__ in, short* __restrict__ out, int n) {
    int i = (blockIdx.x * 256 + threadIdx.x) * 4;
    f32x4 v = *(const f32x4*)(in + i);
    bf16x4 o;
#pragma unroll
    for (int j = 0; j < 4; ++j) o[j] = f2b(v[j]);
    *(bf16x4*)(out + i) = o;
}

// ---------------------------------------------------------------------------
// fp32 in, bf16 transposed out: out[c][r] = in[r][c], in is R x C.
// grid (C/32, R/32), block (32,8)
// ---------------------------------------------------------------------------
__global__ void cvt_transpose(const float* __restrict__ in, short* __restrict__ out,
                              int R, int C) {
    __shared__ short tile[32][33];
    int bx = blockIdx.x * 32, by = blockIdx.y * 32;
    int tx = threadIdx.x, ty = threadIdx.y;
    for (int i = ty; i < 32; i += 8)
        tile[i][tx] = f2b(in[(size_t)(by + i) * C + bx + tx]);
    __syncthreads();
    for (int i = ty; i < 32; i += 8)
        out[(size_t)(bx + i) * R + by + tx] = tile[tx][i];
}

// wq/wk/wv (each 1024x1024 fp32) -> WQKVT (3072x1024 bf16, = [wq^T;wk^T;wv^T])
__global__ void cvt_transpose_qkv(const float* __restrict__ wq, const float* __restrict__ wk,
                                  const float* __restrict__ wv, short* __restrict__ out) {
    __shared__ short tile[32][33];
    const float* in = (blockIdx.z == 0) ? wq : (blockIdx.z == 1) ? wk : wv;
    short* dst = out + (size_t)blockIdx.z * 1024 * 1024;
    int bx = blockIdx.x * 32, by = blockIdx.y * 32;
    int tx = threadIdx.x, ty = threadIdx.y;
    for (int i = ty; i < 32; i += 8)
        tile[i][tx] = f2b(in[(size_t)(by + i) * 1024 + bx + tx]);
    __syncthreads();
    for (int i = ty; i < 32; i += 8)
        dst[(size_t)(bx + i) * 1024 + by + tx] = tile[tx][i];
}

// ---------------------------------------------------------------------------
// GEMM 128x128, BK=64, XOR-swizzled LDS k-chunks.
// mode 0: QKV — bias by col segment, Q scaled, V staged+transposed -> Vt
// mode 1: C = bf16(gelu(acc + bias0[col]))
// Epilogue always stages the tile in LDS, then coalesced 16-B stores.
// ---------------------------------------------------------------------------
__global__ __launch_bounds__(256, 4) void gemm_bt(
    const short* __restrict__ A, const short* __restrict__ Bt,
    const float* __restrict__ bias0, const float* __restrict__ bias1,
    const float* __restrict__ bias2,
    short* __restrict__ C, short* __restrict__ Vt,
    int M, int N, int K, float scale, int mode)
{
    __shared__ short sh[128 * 136];   // 34.8 KB; main loop uses first 16K shorts
    short* As = sh;
    short* Bs = sh + 8192;
    int swz = xcd_swizzle_flat();
    int m0 = (swz % gridDim.x) * 128, n0 = (swz / gridDim.x) * 128;
    int t = threadIdx.x;
    int wave = t >> 6, lane = t & 63, quad = lane >> 4, l16 = lane & 15;
    int wr = (wave >> 1) * 64, wc = (wave & 1) * 64;

    // staging pointers: 4 chunks per wave per buffer
    const short* ap[4]; const short* bp[4]; short* la[4]; short* lb[4];
    int gk = (((lane & 7) ^ (lane >> 3)) * 8);
#pragma unroll
    for (int l = 0; l < 4; ++l) {
        int c = wave * 4 + l;
        int row = c * 8 + (lane >> 3);
        ap[l] = A  + (size_t)(m0 + row) * K + gk;
        bp[l] = Bt + (size_t)(n0 + row) * K + gk;
        la[l] = As + c * 512;
        lb[l] = Bs + c * 512;
    }
    int sw = l16 & 7;   // frag-read swizzle key

    f32x4 acc[4][4] = {};
    for (int k0 = 0; k0 < K; k0 += 64) {
#pragma unroll
        for (int l = 0; l < 4; ++l) { load_lds16(ap[l] + k0, la[l]); load_lds16(bp[l] + k0, lb[l]); }
        __syncthreads();
#pragma unroll
        for (int ks = 0; ks < 2; ++ks) {
            int slot = ((ks * 4 + quad) ^ sw) * 8;
            bf16x8 af[4], bfr[4];
#pragma unroll
            for (int i = 0; i < 4; ++i)
                af[i] = *(bf16x8*)(As + (wr + i * 16 + l16) * 64 + slot);
#pragma unroll
            for (int j = 0; j < 4; ++j)
                bfr[j] = *(bf16x8*)(Bs + (wc + j * 16 + l16) * 64 + slot);
#pragma unroll
            for (int i = 0; i < 4; ++i)
#pragma unroll
                for (int j = 0; j < 4; ++j)
                    acc[i][j] = mfma16(af[i], bfr[j], acc[i][j]);
        }
        __syncthreads();
    }
    // after final barrier, all LDS reads are done -> sh reusable for staging

    int seg0 = n0 >> 10;   // tiles are 128-aligned: never straddle a segment
    if (mode == 1 || seg0 < 2) {
        // ---- stage bf16 tile in LDS: sh[row*136 + col], row/col in [0,128)
        if (mode == 1) {
#pragma unroll
            for (int j = 0; j < 4; ++j) {
                int col = n0 + wc + j * 16 + l16;
                float bs = bias0[col];
#pragma unroll
                for (int i = 0; i < 4; ++i)
#pragma unroll
                    for (int r = 0; r < 4; ++r) {
                        float v = fast_gelu(acc[i][j][r] + bs);
                        sh[(wr + i * 16 + quad * 4 + r) * 136 + wc + j * 16 + l16] = f2b(v);
                    }
            }
        } else {
            float sc = (seg0 == 0) ? scale : 1.0f;
            const float* bpt = (seg0 == 0) ? bias0 : bias1;
#pragma unroll
            for (int j = 0; j < 4; ++j) {
                int col = n0 + wc + j * 16 + l16;
                float bs = bpt[col & 1023];
#pragma unroll
                for (int i = 0; i < 4; ++i)
#pragma unroll
                    for (int r = 0; r < 4; ++r)
                        sh[(wr + i * 16 + quad * 4 + r) * 136 + wc + j * 16 + l16] =
                            f2b((acc[i][j][r] + bs) * sc);
            }
        }
        __syncthreads();
        // ---- coalesced write-out: 2 threads per row, 8 x 16 B each
        int row = t >> 1, half = t & 1;
        const short* src = sh + row * 136 + half * 64;
        short* dst = C + (size_t)(m0 + row) * N + n0 + half * 64;
#pragma unroll
        for (int cgk = 0; cgk < 8; ++cgk)
            *(bf16x8*)(dst + cgk * 8) = *(const bf16x8*)(src + cgk * 8);
    } else {
        // ---- V part: stage TRANSPOSED in LDS (sh[c*136 + row]), then write
        //      Vt (b, h, d, s) with 16-B chunks coalesced along s.
#pragma unroll
        for (int j = 0; j < 4; ++j) {
            int cl = wc + j * 16 + l16;                 // local col in [0,128)
            float bs = bias2[(n0 & 1023) + cl];
#pragma unroll
            for (int i = 0; i < 4; ++i)
#pragma unroll
                for (int r = 0; r < 4; ++r)
                    sh[cl * 136 + wr + i * 16 + quad * 4 + r] = f2b(acc[i][j][r] + bs);
        }
        __syncthreads();
        int h0 = (n0 & 1023) >> 6;                      // first head of tile
        int bb = m0 >> 11, s0 = m0 & 2047;
        int sc = t & 15;                                // s-chunk within tile
#pragma unroll
        for (int cgk = 0; cgk < 8; ++cgk) {
            int cl = (t >> 4) + cgk * 16;               // local col
            int h = h0 + (cl >> 6), d = cl & 63;
            *(bf16x8*)(Vt + (((size_t)(bb * 16 + h)) * 64 + d) * 2048 + s0 + sc * 8) =
                *(const bf16x8*)(sh + cl * 136 + sc * 8);
        }
    }
}

// ---------------------------------------------------------------------------
// GEMM 64x64, BK=64, XOR swizzle, DOUBLE-buffered LDS with counted vmcnt(4):
// tile t+1's 4 loads are issued before computing tile t and stay in flight
// across the barrier (never drained to 0 mid-loop). LDS 32 KB -> still
// 4 blocks/CU, so TLP is preserved (round-7 lesson) AND latency is hidden.
// Cf = A@B + bias + resf (fp32 out). grid (M/64, N/64), 256 thr.
// ---------------------------------------------------------------------------
__global__ __launch_bounds__(256, 4) void gemm64_db(
    const short* __restrict__ A, const short* __restrict__ Bt,
    const float* __restrict__ bias, const float* __restrict__ resf,
    float* __restrict__ Cf, int M, int N, int K)
{
    __shared__ short As[2][64 * 64];
    __shared__ short Bs[2][64 * 64];
    int swz = xcd_swizzle_flat();
    int m0 = (swz % gridDim.x) * 64, n0 = (swz / gridDim.x) * 64;
    int t = threadIdx.x;
    int wave = t >> 6, lane = t & 63, quad = lane >> 4, l16 = lane & 15;
    int wr = (wave >> 1) * 32, wc = (wave & 1) * 32;

    const short* ap[2]; const short* bp[2]; int lo[2];
    int gk = (((lane & 7) ^ (lane >> 3)) * 8);
#pragma unroll
    for (int l = 0; l < 2; ++l) {
        int c = wave * 2 + l;
        int row = c * 8 + (lane >> 3);
        ap[l] = A  + (size_t)(m0 + row) * K + gk;
        bp[l] = Bt + (size_t)(n0 + row) * K + gk;
        lo[l] = c * 512;
    }
    int sw = l16 & 7;

    const int nt = K >> 6;
    // prologue: stage tile 0 into buffer 0
#pragma unroll
    for (int l = 0; l < 2; ++l) { load_lds16(ap[l], &As[0][lo[l]]); load_lds16(bp[l], &Bs[0][lo[l]]); }

    f32x4 acc[2][2] = {};
    for (int ti = 0; ti < nt; ++ti) {
        int cur = ti & 1;
        if (ti + 1 < nt) {
            int k0 = (ti + 1) << 6;
#pragma unroll
            for (int l = 0; l < 2; ++l) {
                load_lds16(ap[l] + k0, &As[cur ^ 1][lo[l]]);
                load_lds16(bp[l] + k0, &Bs[cur ^ 1][lo[l]]);
            }
            asm volatile("s_waitcnt vmcnt(4)" ::: "memory");  // wait cur's loads only
        } else {
            asm volatile("s_waitcnt vmcnt(0)" ::: "memory");
        }
        __builtin_amdgcn_s_barrier();
        asm volatile("" ::: "memory");

        const short* as = &As[cur][0];
        const short* bs = &Bs[cur][0];
#pragma unroll
        for (int ks = 0; ks < 2; ++ks) {
            int slot = ((ks * 4 + quad) ^ sw) * 8;
            bf16x8 af[2], bfr[2];
#pragma unroll
            for (int i = 0; i < 2; ++i)
                af[i] = *(bf16x8*)(as + (wr + i * 16 + l16) * 64 + slot);
#pragma unroll
            for (int j = 0; j < 2; ++j)
                bfr[j] = *(bf16x8*)(bs + (wc + j * 16 + l16) * 64 + slot);
#pragma unroll
            for (int i = 0; i < 2; ++i)
#pragma unroll
                for (int j = 0; j < 2; ++j)
                    acc[i][j] = mfma16(af[i], bfr[j], acc[i][j]);
        }
        asm volatile("" ::: "memory");
        __builtin_amdgcn_s_barrier();   // protect buf cur^1 before next stage
    }

#pragma unroll
    for (int j = 0; j < 2; ++j) {
        int col = n0 + wc + j * 16 + l16;
        float bs = bias[col];
#pragma unroll
        for (int i = 0; i < 2; ++i) {
#pragma unroll
            for (int r = 0; r < 4; ++r) {
                int row = m0 + wr + i * 16 + quad * 4 + r;
                Cf[(size_t)row * N + col] = acc[i][j][r] + bs + resf[(size_t)row * N + col];
            }
        }
    }
}

// ---------------------------------------------------------------------------
// Windowed attention with global column (structure unchanged since round 4).
// ---------------------------------------------------------------------------
__global__ __launch_bounds__(256, 2) void attn_kernel(
    const short* __restrict__ QKV, const short* __restrict__ Vt,
    const int* __restrict__ mask,
    const float* __restrict__ bk, const float* __restrict__ bv,
    short* __restrict__ attn)
{
    extern __shared__ char smem[];
    short* PsQ = (short*)smem;
    short* KV  = (short*)(smem + 34816);
    float* gkf = (float*)(smem + 53248);
    float* gvf = (float*)(smem + 53504);

    int blk = blockIdx.x;
    int c = blk & 15, h = (blk >> 4) & 15, b = blk >> 8;
    int t = threadIdx.x;
    int wave = t >> 6, lane = t & 63, quad = lane >> 4, l16 = lane & 15;
    int q0 = c * 128;
    const int bs_off = b * 2048;
    const short* Q = QKV + h * 64;
    const short* K = QKV + 1024 + h * 64;

#pragma unroll
    for (int l = 0; l < 4; ++l) {
        int idx = l * 256 + t;
        int p = idx >> 3, dc = (idx & 7) * 8;
        *(bf16x8*)(PsQ + p * 72 + dc) =
            *(const bf16x8*)(Q + ((size_t)(bs_off + q0 + p)) * 3072 + dc);
    }
    if (t < 64) { gkf[t] = bk[h * 64 + t]; gvf[t] = bv[h * 64 + t]; }
    __syncthreads();

    bf16x8 aq[2][2];
#pragma unroll
    for (int ti = 0; ti < 2; ++ti)
#pragma unroll
        for (int ks = 0; ks < 2; ++ks)
            aq[ti][ks] = *(bf16x8*)(PsQ + (wave * 32 + ti * 16 + l16) * 72 + ks * 32 + quad * 8);

    float s_g[2][4];
#pragma unroll
    for (int ti = 0; ti < 2; ++ti)
#pragma unroll
        for (int r = 0; r < 4; ++r) {
            int row = wave * 32 + ti * 16 + quad * 4 + r;
            float part = 0.f;
#pragma unroll
            for (int dd = 0; dd < 4; ++dd) {
                int d = l16 * 4 + dd;
                part += b2f(PsQ[row * 72 + d]) * gkf[d];
            }
#pragma unroll
            for (int dsh = 1; dsh < 16; dsh <<= 1) part += __shfl_xor(part, dsh);
            s_g[ti][r] = part;
        }

    f32x4 o_acc[2][4] = {};
    float m_run[2][4], l_run[2][4];
#pragma unroll
    for (int ti = 0; ti < 2; ++ti)
#pragma unroll
        for (int r = 0; r < 4; ++r) { m_run[ti][r] = NEGF; l_run[ti][r] = 0.f; }

    int kt_beg = (q0 == 0) ? 1 : 0;
    int kt_end = (q0 + 256 > 2048) ? 2 : 3;
    for (int kt = kt_beg; kt < kt_end; ++kt) {
        int jb = q0 + (kt - 1) * 128;
        __syncthreads();
#pragma unroll
        for (int l = 0; l < 4; ++l) {
            int idx = l * 256 + t;
            int p = idx >> 3, dc = (idx & 7) * 8;
            *(bf16x8*)(KV + p * 72 + dc) =
                *(const bf16x8*)(K + ((size_t)(bs_off + jb + p)) * 3072 + dc);
        }
        __syncthreads();

        f32x4 s_acc[2][8] = {};
#pragma unroll
        for (int ks = 0; ks < 2; ++ks) {
            bf16x8 bk8[8];
#pragma unroll
            for (int tj = 0; tj < 8; ++tj)
                bk8[tj] = *(bf16x8*)(KV + (tj * 16 + l16) * 72 + ks * 32 + quad * 8);
#pragma unroll
            for (int ti = 0; ti < 2; ++ti)
#pragma unroll
                for (int tj = 0; tj < 8; ++tj)
                    s_acc[ti][tj] = mfma16(aq[ti][ks], bk8[tj], s_acc[ti][tj]);
        }

        float negj[8]; int jcol[8];
#pragma unroll
        for (int tj = 0; tj < 8; ++tj) {
            jcol[tj] = jb + tj * 16 + l16;
            negj[tj] = (mask[bs_off + jcol[tj]] != 0) ? NEGF : 0.f;
        }
        float tmax[2][4];
#pragma unroll
        for (int ti = 0; ti < 2; ++ti)
#pragma unroll
            for (int r = 0; r < 4; ++r) tmax[ti][r] = NEGF;
#pragma unroll
        for (int ti = 0; ti < 2; ++ti) {
            int irow_base = q0 + wave * 32 + ti * 16 + quad * 4;
#pragma unroll
            for (int tj = 0; tj < 8; ++tj)
#pragma unroll
                for (int r = 0; r < 4; ++r) {
                    int dj = jcol[tj] - (irow_base + r);
                    float sc = (dj >= -128 && dj <= 128) ? (s_acc[ti][tj][r] + negj[tj]) : NEGF;
                    s_acc[ti][tj][r] = sc;
                    tmax[ti][r] = fmaxf(tmax[ti][r], sc);
                }
        }
#pragma unroll
        for (int ti = 0; ti < 2; ++ti)
#pragma unroll
            for (int r = 0; r < 4; ++r)
#pragma unroll
                for (int dsh = 1; dsh < 16; dsh <<= 1)
                    tmax[ti][r] = fmaxf(tmax[ti][r], __shfl_xor(tmax[ti][r], dsh));

        float alpha[2][4], lsum[2][4];
#pragma unroll
        for (int ti = 0; ti < 2; ++ti)
#pragma unroll
            for (int r = 0; r < 4; ++r) {
                float mnew = fmaxf(m_run[ti][r], tmax[ti][r]);
                alpha[ti][r] = safe_exp(m_run[ti][r] - mnew);
                m_run[ti][r] = mnew;
                lsum[ti][r] = 0.f;
            }
#pragma unroll
        for (int ti = 0; ti < 2; ++ti)
#pragma unroll
            for (int tj = 0; tj < 8; ++tj)
#pragma unroll
                for (int r = 0; r < 4; ++r) {
                    float p = safe_exp(s_acc[ti][tj][r] - m_run[ti][r]);
                    lsum[ti][r] += p;
                    PsQ[(wave * 32 + ti * 16 + quad * 4 + r) * 136 + tj * 16 + l16] = f2b(p);
                }
#pragma unroll
        for (int ti = 0; ti < 2; ++ti)
#pragma unroll
            for (int r = 0; r < 4; ++r) {
#pragma unroll
                for (int dsh = 1; dsh < 16; dsh <<= 1) lsum[ti][r] += __shfl_xor(lsum[ti][r], dsh);
                l_run[ti][r] = l_run[ti][r] * alpha[ti][r] + lsum[ti][r];
            }
#pragma unroll
        for (int ti = 0; ti < 2; ++ti)
#pragma unroll
            for (int dj = 0; dj < 4; ++dj)
#pragma unroll
                for (int r = 0; r < 4; ++r) o_acc[ti][dj][r] *= alpha[ti][r];

        __syncthreads();
#pragma unroll
        for (int l = 0; l < 4; ++l) {
            int idx = l * 256 + t;
            int d = idx >> 4, kc = (idx & 15) * 8;
            *(bf16x8*)(KV + d * 136 + kc) =
                *(const bf16x8*)(Vt + ((size_t)(b * 16 + h) * 64 + d) * 2048 + jb + kc);
        }
        __syncthreads();
#pragma unroll
        for (int ks = 0; ks < 4; ++ks) {
            bf16x8 ap[2], bv8[4];
#pragma unroll
            for (int ti = 0; ti < 2; ++ti)
                ap[ti] = *(bf16x8*)(PsQ + (wave * 32 + ti * 16 + l16) * 136 + ks * 32 + quad * 8);
#pragma unroll
            for (int dj = 0; dj < 4; ++dj)
                bv8[dj] = *(bf16x8*)(KV + (dj * 16 + l16) * 136 + ks * 32 + quad * 8);
#pragma unroll
            for (int ti = 0; ti < 2; ++ti)
#pragma unroll
                for (int dj = 0; dj < 4; ++dj)
                    o_acc[ti][dj] = mfma16(ap[ti], bv8[dj], o_acc[ti][dj]);
        }
    }

#pragma unroll
    for (int ti = 0; ti < 2; ++ti) {
        int irow_base = q0 + wave * 32 + ti * 16 + quad * 4;
#pragma unroll
        for (int r = 0; r < 4; ++r) {
            int i = irow_base + r;
            float m2 = fmaxf(m_run[ti][r], s_g[ti][r]);
            float pg = safe_exp(s_g[ti][r] - m2);
            float al = safe_exp(m_run[ti][r] - m2);
            float l2 = l_run[ti][r] * al + pg;
            float invl = 1.f / fmaxf(l2, 1e-30f);
            float qm = (mask[bs_off + i] > 0) ? 0.f : 1.f;
#pragma unroll
            for (int dj = 0; dj < 4; ++dj) {
                int d = dj * 16 + l16;
                float val = (o_acc[ti][dj][r] * al + pg * gvf[d]) * invl * qm;
                attn[((size_t)(bs_off + i)) * 1024 + h * 64 + d] = f2b(val);
            }
        }
    }
}

// ---------------------------------------------------------------------------
// y = LN(x + attn) * g + b ; writes bf16 (GEMM input) AND fp32 (residual).
// ---------------------------------------------------------------------------
__global__ __launch_bounds__(256) void resid_ln(
    const float* __restrict__ x, const short* __restrict__ attn,
    const float* __restrict__ g, const float* __restrict__ be,
    short* __restrict__ yb, float* __restrict__ yf)
{
    int row = blockIdx.x, t = threadIdx.x;
    int lane = t & 63, wave = t >> 6;
    const size_t base = (size_t)row * 1024;
    float v[4]; float s = 0.f, s2 = 0.f;
#pragma unroll
    for (int i = 0; i < 4; ++i) {
        int c = i * 256 + t;
        float val = x[base + c] + b2f(attn[base + c]);
        v[i] = val; s += val; s2 += val * val;
    }
#pragma unroll
    for (int off = 32; off > 0; off >>= 1) { s += __shfl_xor(s, off); s2 += __shfl_xor(s2, off); }
    __shared__ float red[8];
    if (lane == 0) { red[wave] = s; red[4 + wave] = s2; }
    __syncthreads();
    s  = red[0] + red[1] + red[2] + red[3];
    s2 = red[4] + red[5] + red[6] + red[7];
    float mu  = s * (1.f / 1024.f);
    float var = s2 * (1.f / 1024.f) - mu * mu;
    float inv = rsqrtf(fmaxf(var, 0.f) + 1e-5f);
#pragma unroll
    for (int i = 0; i < 4; ++i) {
        int c = i * 256 + t;
        float o = (v[i] - mu) * inv * g[c] + be[c];
        yb[base + c] = f2b(o);
        yf[base + c] = o;
    }
}

// ---------------------------------------------------------------------------
// workspace layout, units = bf16 elements (2 B). total 47M units = 94 MB.
// ---------------------------------------------------------------------------
static constexpr size_t MEG      = 1048576;
static constexpr size_t OFF_WQKV = 0;            // 3M  (3072x1024 bf16)
static constexpr size_t OFF_W1T  = 3 * MEG;      // 4M
static constexpr size_t OFF_W2T  = 7 * MEG;      // 4M
static constexpr size_t OFF_XB   = 11 * MEG;     // 4M
static constexpr size_t OFF_QKV  = 15 * MEG;     // 12M (4096x3072 bf16; V third unused)
static constexpr size_t OFF_VT   = 27 * MEG;     // 4M
static constexpr size_t OFF_ATT  = 31 * MEG;     // 4M
static constexpr size_t OFF_YN   = 35 * MEG;     // 4M (bf16)
static constexpr size_t OFF_YF   = 39 * MEG;     // 8M units = 4M fp32
static constexpr size_t OFF_H    = OFF_QKV;      // 16M, aliases QKV+VT (dead)

extern "C" void kernel_launch(void* const* d_in, const int* in_sizes, int n_in,
                              void* d_out, int out_size, void* d_ws, size_t ws_size,
                              hipStream_t stream) {
    (void)in_sizes; (void)n_in; (void)out_size; (void)ws_size;
    const float* x    = (const float*)d_in[0];
    const int*   mask = (const int*)  d_in[1];
    const float* wq   = (const float*)d_in[2];
    const float* bq   = (const float*)d_in[3];
    const float* wk   = (const float*)d_in[4];
    const float* bk   = (const float*)d_in[5];
    const float* wv   = (const float*)d_in[6];
    const float* bv   = (const float*)d_in[7];
    // d_in[8..13] (global-query branch) are provably dead for the output
    const float* lng  = (const float*)d_in[14];
    const float* lnb  = (const float*)d_in[15];
    const float* w1   = (const float*)d_in[16];
    const float* b1   = (const float*)d_in[17];
    const float* w2   = (const float*)d_in[18];
    const float* b2   = (const float*)d_in[19];
    short* ws  = (short*)d_ws;
    float* out = (float*)d_out;

    dim3 tb(32, 8);
    cvt_transpose_qkv<<<dim3(32, 32, 3), tb, 0, stream>>>(wq, wk, wv, ws + OFF_WQKV);
    cvt_transpose<<<dim3(128, 32), tb, 0, stream>>>(w1, ws + OFF_W1T, 1024, 4096);
    cvt_transpose<<<dim3(32, 128), tb, 0, stream>>>(w2, ws + OFF_W2T, 4096, 1024);
    cvt_f32_bf16<<<4096, 256, 0, stream>>>(x, ws + OFF_XB, 4194304);

    // QKV = x @ [wq|wk|wv] + [bq|bk|bv]; Q scaled 1/8; V staged -> Vt fused
    gemm_bt<<<dim3(32, 24), 256, 0, stream>>>(ws + OFF_XB, ws + OFF_WQKV,
                                              bq, bk, bv,
                                              ws + OFF_QKV, ws + OFF_VT,
                                              4096, 3072, 1024, 0.125f, 0);

    attn_kernel<<<512, 256, 53760, stream>>>(ws + OFF_QKV, ws + OFF_VT,
                                             mask, bk, bv, ws + OFF_ATT);

    resid_ln<<<4096, 256, 0, stream>>>(x, ws + OFF_ATT, lng, lnb,
                                       ws + OFF_YN, (float*)(ws + OFF_YF));

    // h = gelu(y@w1 + b1)
    gemm_bt<<<dim3(32, 32), 256, 0, stream>>>(ws + OFF_YN, ws + OFF_W1T,
                                              b1, nullptr, nullptr,
                                              ws + OFF_H, nullptr,
                                              4096, 4096, 1024, 1.0f, 1);
    // out = y + h@w2 + b2 (64^2 tile, double-buffered, counted vmcnt)
    gemm64_db<<<dim3(64, 16), 256, 0, stream>>>(ws + OFF_H, ws + OFF_W2T,
                                                b2, (const float*)(ws + OFF_YF),
                                                out, 4096, 1024, 4096);
}

// Round 6
// 339.510 us; speedup vs baseline: 1.0736x; 1.0029x over previous
//
#include <hip/hip_runtime.h>

// ---------------------------------------------------------------------------
// HFLongFormerSelfAttentionBlock — MI355X implementation (round 12)
//
// I/O fp32; internal bf16 MFMA, fp32 accumulation/epilogues.
// Round-12: gemm64_db XCD swizzle REVERTED (single change). rocprof r5:
// FETCH 59->144 MB under the swizzle — each XCD streamed the whole 33.5 MB
// A through its 4 MB L2 (remap gave XCD k all m-tiles x 2 n-tiles). The
// natural fid%8 order partitions A 4 MB/XCD = exact L2 fit (r0: 59 MB).
// Keeps round-10's double-buffer + counted vmcnt(4). gemm_bt keeps its
// swizzle (per-XCD footprints symmetric for those shapes; dispatches
// improved in r5).
// ---------------------------------------------------------------------------

using bf16x8 = __attribute__((ext_vector_type(8))) short;
using bf16x4 = __attribute__((ext_vector_type(4))) short;
using f32x4  = __attribute__((ext_vector_type(4))) float;

__device__ __forceinline__ float b2f(short s) {
    return __uint_as_float(((unsigned int)(unsigned short)s) << 16);
}
__device__ __forceinline__ short f2b(float f) {
    unsigned int u = __float_as_uint(f);
    u += 0x7fffu + ((u >> 16) & 1u);   // round-to-nearest-even
    return (short)(u >> 16);
}
__device__ __forceinline__ f32x4 mfma16(bf16x8 a, bf16x8 b, f32x4 c) {
    return __builtin_amdgcn_mfma_f32_16x16x32_bf16(a, b, c, 0, 0, 0);
}
__device__ __forceinline__ float safe_exp(float x) {
    return expf((x <= 0.f) ? x : 0.f);
}
// gelu(v) = 0.5 v (1 + erf(v/sqrt2)); erf via A&S 7.1.25 (|err| <= 2.5e-5,
// branch-free: rcp + exp + 5 fma). 100x below bf16 output quantization.
__device__ __forceinline__ float fast_gelu(float v) {
    float z  = fabsf(v) * 0.70710678118f;
    float t  = __builtin_amdgcn_rcpf(fmaf(0.47047f, z, 1.f));
    float e  = __expf(-z * z);
    float p  = t * fmaf(t, fmaf(t, 0.7478556f, -0.0958798f), 0.3480242f);
    float er = fmaf(-p, e, 1.f);                  // erf(|z|)
    er = (v < 0.f) ? -er : er;
    return 0.5f * v * (1.f + er);
}
// async global->LDS, 16 B per lane; LDS dest = wave-uniform base + lane*16
__device__ __forceinline__ void load_lds16(const short* g, short* l) {
    __builtin_amdgcn_global_load_lds((const __attribute__((address_space(1))) void*)g,
                                     (__attribute__((address_space(3))) void*)l, 16, 0, 0);
}
// XCD-aware bijective swizzle of the flat block id (grids here are %8==0).
__device__ __forceinline__ int xcd_swizzle_flat() {
    int fid = blockIdx.x + blockIdx.y * gridDim.x;
    int nwg = gridDim.x * gridDim.y;
    return (fid & 7) * (nwg >> 3) + (fid >> 3);
}
#define NEGF (-3.0e38f)

// ---------------------------------------------------------------------------
// fp32 -> bf16 elementwise convert (n multiple of 1024). grid n/1024, 256 thr
// ---------------------------------------------------------------------------
__global__ void cvt_f32_bf16(const float* __restrict__ in, short* __restrict__ out, int n) {
    int i = (blockIdx.x * 256 + threadIdx.x) * 4;
    f32x4 v = *(const f32x4*)(in + i);
    bf16x4 o;
#pragma unroll
    for (int j = 0; j < 4; ++j) o[j] = f2b(v[j]);
    *(bf16x4*)(out + i) = o;
}

// ---------------------------------------------------------------------------
// fp32 in, bf16 transposed out: out[c][r] = in[r][c], in is R x C.
// grid (C/32, R/32), block (32,8)
// ---------------------------------------------------------------------------
__global__ void cvt_transpose(const float* __restrict__ in, short* __restrict__ out,
                              int R, int C) {
    __shared__ short tile[32][33];
    int bx = blockIdx.x * 32, by = blockIdx.y * 32;
    int tx = threadIdx.x, ty = threadIdx.y;
    for (int i = ty; i < 32; i += 8)
        tile[i][tx] = f2b(in[(size_t)(by + i) * C + bx + tx]);
    __syncthreads();
    for (int i = ty; i < 32; i += 8)
        out[(size_t)(bx + i) * R + by + tx] = tile[tx][i];
}

// wq/wk/wv (each 1024x1024 fp32) -> WQKVT (3072x1024 bf16, = [wq^T;wk^T;wv^T])
__global__ void cvt_transpose_qkv(const float* __restrict__ wq, const float* __restrict__ wk,
                                  const float* __restrict__ wv, short* __restrict__ out) {
    __shared__ short tile[32][33];
    const float* in = (blockIdx.z == 0) ? wq : (blockIdx.z == 1) ? wk : wv;
    short* dst = out + (size_t)blockIdx.z * 1024 * 1024;
    int bx = blockIdx.x * 32, by = blockIdx.y * 32;
    int tx = threadIdx.x, ty = threadIdx.y;
    for (int i = ty; i < 32; i += 8)
        tile[i][tx] = f2b(in[(size_t)(by + i) * 1024 + bx + tx]);
    __syncthreads();
    for (int i = ty; i < 32; i += 8)
        dst[(size_t)(bx + i) * 1024 + by + tx] = tile[tx][i];
}

// ---------------------------------------------------------------------------
// GEMM 128x128, BK=64, XOR-swizzled LDS k-chunks.
// mode 0: QKV — bias by col segment, Q scaled, V staged+transposed -> Vt
// mode 1: C = bf16(gelu(acc + bias0[col]))
// Epilogue always stages the tile in LDS, then coalesced 16-B stores.
// ---------------------------------------------------------------------------
__global__ __launch_bounds__(256, 4) void gemm_bt(
    const short* __restrict__ A, const short* __restrict__ Bt,
    const float* __restrict__ bias0, const float* __restrict__ bias1,
    const float* __restrict__ bias2,
    short* __restrict__ C, short* __restrict__ Vt,
    int M, int N, int K, float scale, int mode)
{
    __shared__ short sh[128 * 136];   // 34.8 KB; main loop uses first 16K shorts
    short* As = sh;
    short* Bs = sh + 8192;
    int swz = xcd_swizzle_flat();
    int m0 = (swz % gridDim.x) * 128, n0 = (swz / gridDim.x) * 128;
    int t = threadIdx.x;
    int wave = t >> 6, lane = t & 63, quad = lane >> 4, l16 = lane & 15;
    int wr = (wave >> 1) * 64, wc = (wave & 1) * 64;

    // staging pointers: 4 chunks per wave per buffer
    const short* ap[4]; const short* bp[4]; short* la[4]; short* lb[4];
    int gk = (((lane & 7) ^ (lane >> 3)) * 8);
#pragma unroll
    for (int l = 0; l < 4; ++l) {
        int c = wave * 4 + l;
        int row = c * 8 + (lane >> 3);
        ap[l] = A  + (size_t)(m0 + row) * K + gk;
        bp[l] = Bt + (size_t)(n0 + row) * K + gk;
        la[l] = As + c * 512;
        lb[l] = Bs + c * 512;
    }
    int sw = l16 & 7;   // frag-read swizzle key

    f32x4 acc[4][4] = {};
    for (int k0 = 0; k0 < K; k0 += 64) {
#pragma unroll
        for (int l = 0; l < 4; ++l) { load_lds16(ap[l] + k0, la[l]); load_lds16(bp[l] + k0, lb[l]); }
        __syncthreads();
#pragma unroll
        for (int ks = 0; ks < 2; ++ks) {
            int slot = ((ks * 4 + quad) ^ sw) * 8;
            bf16x8 af[4], bfr[4];
#pragma unroll
            for (int i = 0; i < 4; ++i)
                af[i] = *(bf16x8*)(As + (wr + i * 16 + l16) * 64 + slot);
#pragma unroll
            for (int j = 0; j < 4; ++j)
                bfr[j] = *(bf16x8*)(Bs + (wc + j * 16 + l16) * 64 + slot);
#pragma unroll
            for (int i = 0; i < 4; ++i)
#pragma unroll
                for (int j = 0; j < 4; ++j)
                    acc[i][j] = mfma16(af[i], bfr[j], acc[i][j]);
        }
        __syncthreads();
    }
    // after final barrier, all LDS reads are done -> sh reusable for staging

    int seg0 = n0 >> 10;   // tiles are 128-aligned: never straddle a segment
    if (mode == 1 || seg0 < 2) {
        // ---- stage bf16 tile in LDS: sh[row*136 + col], row/col in [0,128)
        if (mode == 1) {
#pragma unroll
            for (int j = 0; j < 4; ++j) {
                int col = n0 + wc + j * 16 + l16;
                float bs = bias0[col];
#pragma unroll
                for (int i = 0; i < 4; ++i)
#pragma unroll
                    for (int r = 0; r < 4; ++r) {
                        float v = fast_gelu(acc[i][j][r] + bs);
                        sh[(wr + i * 16 + quad * 4 + r) * 136 + wc + j * 16 + l16] = f2b(v);
                    }
            }
        } else {
            float sc = (seg0 == 0) ? scale : 1.0f;
            const float* bpt = (seg0 == 0) ? bias0 : bias1;
#pragma unroll
            for (int j = 0; j < 4; ++j) {
                int col = n0 + wc + j * 16 + l16;
                float bs = bpt[col & 1023];
#pragma unroll
                for (int i = 0; i < 4; ++i)
#pragma unroll
                    for (int r = 0; r < 4; ++r)
                        sh[(wr + i * 16 + quad * 4 + r) * 136 + wc + j * 16 + l16] =
                            f2b((acc[i][j][r] + bs) * sc);
            }
        }
        __syncthreads();
        // ---- coalesced write-out: 2 threads per row, 8 x 16 B each
        int row = t >> 1, half = t & 1;
        const short* src = sh + row * 136 + half * 64;
        short* dst = C + (size_t)(m0 + row) * N + n0 + half * 64;
#pragma unroll
        for (int cgk = 0; cgk < 8; ++cgk)
            *(bf16x8*)(dst + cgk * 8) = *(const bf16x8*)(src + cgk * 8);
    } else {
        // ---- V part: stage TRANSPOSED in LDS (sh[c*136 + row]), then write
        //      Vt (b, h, d, s) with 16-B chunks coalesced along s.
#pragma unroll
        for (int j = 0; j < 4; ++j) {
            int cl = wc + j * 16 + l16;                 // local col in [0,128)
            float bs = bias2[(n0 & 1023) + cl];
#pragma unroll
            for (int i = 0; i < 4; ++i)
#pragma unroll
                for (int r = 0; r < 4; ++r)
                    sh[cl * 136 + wr + i * 16 + quad * 4 + r] = f2b(acc[i][j][r] + bs);
        }
        __syncthreads();
        int h0 = (n0 & 1023) >> 6;                      // first head of tile
        int bb = m0 >> 11, s0 = m0 & 2047;
        int sc = t & 15;                                // s-chunk within tile
#pragma unroll
        for (int cgk = 0; cgk < 8; ++cgk) {
            int cl = (t >> 4) + cgk * 16;               // local col
            int h = h0 + (cl >> 6), d = cl & 63;
            *(bf16x8*)(Vt + (((size_t)(bb * 16 + h)) * 64 + d) * 2048 + s0 + sc * 8) =
                *(const bf16x8*)(sh + cl * 136 + sc * 8);
        }
    }
}

// ---------------------------------------------------------------------------
// GEMM 64x64, BK=64, XOR swizzle, DOUBLE-buffered LDS with counted vmcnt(4).
// NATURAL block order (no XCD swizzle): fid%8 partitions A 4 MB per XCD =
// exact L2 fit (measured r0: FETCH 59 MB ideal; swizzled r5: 144 MB thrash).
// Cf = A@B + bias + resf (fp32 out). grid (M/64, N/64), 256 thr.
// ---------------------------------------------------------------------------
__global__ __launch_bounds__(256, 4) void gemm64_db(
    const short* __restrict__ A, const short* __restrict__ Bt,
    const float* __restrict__ bias, const float* __restrict__ resf,
    float* __restrict__ Cf, int M, int N, int K)
{
    __shared__ short As[2][64 * 64];
    __shared__ short Bs[2][64 * 64];
    int m0 = blockIdx.x * 64, n0 = blockIdx.y * 64;
    int t = threadIdx.x;
    int wave = t >> 6, lane = t & 63, quad = lane >> 4, l16 = lane & 15;
    int wr = (wave >> 1) * 32, wc = (wave & 1) * 32;

    const short* ap[2]; const short* bp[2]; int lo[2];
    int gk = (((lane & 7) ^ (lane >> 3)) * 8);
#pragma unroll
    for (int l = 0; l < 2; ++l) {
        int c = wave * 2 + l;
        int row = c * 8 + (lane >> 3);
        ap[l] = A  + (size_t)(m0 + row) * K + gk;
        bp[l] = Bt + (size_t)(n0 + row) * K + gk;
        lo[l] = c * 512;
    }
    int sw = l16 & 7;

    const int nt = K >> 6;
    // prologue: stage tile 0 into buffer 0
#pragma unroll
    for (int l = 0; l < 2; ++l) { load_lds16(ap[l], &As[0][lo[l]]); load_lds16(bp[l], &Bs[0][lo[l]]); }

    f32x4 acc[2][2] = {};
    for (int ti = 0; ti < nt; ++ti) {
        int cur = ti & 1;
        if (ti + 1 < nt) {
            int k0 = (ti + 1) << 6;
#pragma unroll
            for (int l = 0; l < 2; ++l) {
                load_lds16(ap[l] + k0, &As[cur ^ 1][lo[l]]);
                load_lds16(bp[l] + k0, &Bs[cur ^ 1][lo[l]]);
            }
            asm volatile("s_waitcnt vmcnt(4)" ::: "memory");  // wait cur's loads only
        } else {
            asm volatile("s_waitcnt vmcnt(0)" ::: "memory");
        }
        __builtin_amdgcn_s_barrier();
        asm volatile("" ::: "memory");

        const short* as = &As[cur][0];
        const short* bs = &Bs[cur][0];
#pragma unroll
        for (int ks = 0; ks < 2; ++ks) {
            int slot = ((ks * 4 + quad) ^ sw) * 8;
            bf16x8 af[2], bfr[2];
#pragma unroll
            for (int i = 0; i < 2; ++i)
                af[i] = *(bf16x8*)(as + (wr + i * 16 + l16) * 64 + slot);
#pragma unroll
            for (int j = 0; j < 2; ++j)
                bfr[j] = *(bf16x8*)(bs + (wc + j * 16 + l16) * 64 + slot);
#pragma unroll
            for (int i = 0; i < 2; ++i)
#pragma unroll
                for (int j = 0; j < 2; ++j)
                    acc[i][j] = mfma16(af[i], bfr[j], acc[i][j]);
        }
        asm volatile("" ::: "memory");
        __builtin_amdgcn_s_barrier();   // protect buf cur^1 before next stage
    }

#pragma unroll
    for (int j = 0; j < 2; ++j) {
        int col = n0 + wc + j * 16 + l16;
        float bs = bias[col];
#pragma unroll
        for (int i = 0; i < 2; ++i) {
#pragma unroll
            for (int r = 0; r < 4; ++r) {
                int row = m0 + wr + i * 16 + quad * 4 + r;
                Cf[(size_t)row * N + col] = acc[i][j][r] + bs + resf[(size_t)row * N + col];
            }
        }
    }
}

// ---------------------------------------------------------------------------
// Windowed attention with global column (structure unchanged since round 4).
// ---------------------------------------------------------------------------
__global__ __launch_bounds__(256, 2) void attn_kernel(
    const short* __restrict__ QKV, const short* __restrict__ Vt,
    const int* __restrict__ mask,
    const float* __restrict__ bk, const float* __restrict__ bv,
    short* __restrict__ attn)
{
    extern __shared__ char smem[];
    short* PsQ = (short*)smem;
    short* KV  = (short*)(smem + 34816);
    float* gkf = (float*)(smem + 53248);
    float* gvf = (float*)(smem + 53504);

    int blk = blockIdx.x;
    int c = blk & 15, h = (blk >> 4) & 15, b = blk >> 8;
    int t = threadIdx.x;
    int wave = t >> 6, lane = t & 63, quad = lane >> 4, l16 = lane & 15;
    int q0 = c * 128;
    const int bs_off = b * 2048;
    const short* Q = QKV + h * 64;
    const short* K = QKV + 1024 + h * 64;

#pragma unroll
    for (int l = 0; l < 4; ++l) {
        int idx = l * 256 + t;
        int p = idx >> 3, dc = (idx & 7) * 8;
        *(bf16x8*)(PsQ + p * 72 + dc) =
            *(const bf16x8*)(Q + ((size_t)(bs_off + q0 + p)) * 3072 + dc);
    }
    if (t < 64) { gkf[t] = bk[h * 64 + t]; gvf[t] = bv[h * 64 + t]; }
    __syncthreads();

    bf16x8 aq[2][2];
#pragma unroll
    for (int ti = 0; ti < 2; ++ti)
#pragma unroll
        for (int ks = 0; ks < 2; ++ks)
            aq[ti][ks] = *(bf16x8*)(PsQ + (wave * 32 + ti * 16 + l16) * 72 + ks * 32 + quad * 8);

    float s_g[2][4];
#pragma unroll
    for (int ti = 0; ti < 2; ++ti)
#pragma unroll
        for (int r = 0; r < 4; ++r) {
            int row = wave * 32 + ti * 16 + quad * 4 + r;
            float part = 0.f;
#pragma unroll
            for (int dd = 0; dd < 4; ++dd) {
                int d = l16 * 4 + dd;
                part += b2f(PsQ[row * 72 + d]) * gkf[d];
            }
#pragma unroll
            for (int dsh = 1; dsh < 16; dsh <<= 1) part += __shfl_xor(part, dsh);
            s_g[ti][r] = part;
        }

    f32x4 o_acc[2][4] = {};
    float m_run[2][4], l_run[2][4];
#pragma unroll
    for (int ti = 0; ti < 2; ++ti)
#pragma unroll
        for (int r = 0; r < 4; ++r) { m_run[ti][r] = NEGF; l_run[ti][r] = 0.f; }

    int kt_beg = (q0 == 0) ? 1 : 0;
    int kt_end = (q0 + 256 > 2048) ? 2 : 3;
    for (int kt = kt_beg; kt < kt_end; ++kt) {
        int jb = q0 + (kt - 1) * 128;
        __syncthreads();
#pragma unroll
        for (int l = 0; l < 4; ++l) {
            int idx = l * 256 + t;
            int p = idx >> 3, dc = (idx & 7) * 8;
            *(bf16x8*)(KV + p * 72 + dc) =
                *(const bf16x8*)(K + ((size_t)(bs_off + jb + p)) * 3072 + dc);
        }
        __syncthreads();

        f32x4 s_acc[2][8] = {};
#pragma unroll
        for (int ks = 0; ks < 2; ++ks) {
            bf16x8 bk8[8];
#pragma unroll
            for (int tj = 0; tj < 8; ++tj)
                bk8[tj] = *(bf16x8*)(KV + (tj * 16 + l16) * 72 + ks * 32 + quad * 8);
#pragma unroll
            for (int ti = 0; ti < 2; ++ti)
#pragma unroll
                for (int tj = 0; tj < 8; ++tj)
                    s_acc[ti][tj] = mfma16(aq[ti][ks], bk8[tj], s_acc[ti][tj]);
        }

        float negj[8]; int jcol[8];
#pragma unroll
        for (int tj = 0; tj < 8; ++tj) {
            jcol[tj] = jb + tj * 16 + l16;
            negj[tj] = (mask[bs_off + jcol[tj]] != 0) ? NEGF : 0.f;
        }
        float tmax[2][4];
#pragma unroll
        for (int ti = 0; ti < 2; ++ti)
#pragma unroll
            for (int r = 0; r < 4; ++r) tmax[ti][r] = NEGF;
#pragma unroll
        for (int ti = 0; ti < 2; ++ti) {
            int irow_base = q0 + wave * 32 + ti * 16 + quad * 4;
#pragma unroll
            for (int tj = 0; tj < 8; ++tj)
#pragma unroll
                for (int r = 0; r < 4; ++r) {
                    int dj = jcol[tj] - (irow_base + r);
                    float sc = (dj >= -128 && dj <= 128) ? (s_acc[ti][tj][r] + negj[tj]) : NEGF;
                    s_acc[ti][tj][r] = sc;
                    tmax[ti][r] = fmaxf(tmax[ti][r], sc);
                }
        }
#pragma unroll
        for (int ti = 0; ti < 2; ++ti)
#pragma unroll
            for (int r = 0; r < 4; ++r)
#pragma unroll
                for (int dsh = 1; dsh < 16; dsh <<= 1)
                    tmax[ti][r] = fmaxf(tmax[ti][r], __shfl_xor(tmax[ti][r], dsh));

        float alpha[2][4], lsum[2][4];
#pragma unroll
        for (int ti = 0; ti < 2; ++ti)
#pragma unroll
            for (int r = 0; r < 4; ++r) {
                float mnew = fmaxf(m_run[ti][r], tmax[ti][r]);
                alpha[ti][r] = safe_exp(m_run[ti][r] - mnew);
                m_run[ti][r] = mnew;
                lsum[ti][r] = 0.f;
            }
#pragma unroll
        for (int ti = 0; ti < 2; ++ti)
#pragma unroll
            for (int tj = 0; tj < 8; ++tj)
#pragma unroll
                for (int r = 0; r < 4; ++r) {
                    float p = safe_exp(s_acc[ti][tj][r] - m_run[ti][r]);
                    lsum[ti][r] += p;
                    PsQ[(wave * 32 + ti * 16 + quad * 4 + r) * 136 + tj * 16 + l16] = f2b(p);
                }
#pragma unroll
        for (int ti = 0; ti < 2; ++ti)
#pragma unroll
            for (int r = 0; r < 4; ++r) {
#pragma unroll
                for (int dsh = 1; dsh < 16; dsh <<= 1) lsum[ti][r] += __shfl_xor(lsum[ti][r], dsh);
                l_run[ti][r] = l_run[ti][r] * alpha[ti][r] + lsum[ti][r];
            }
#pragma unroll
        for (int ti = 0; ti < 2; ++ti)
#pragma unroll
            for (int dj = 0; dj < 4; ++dj)
#pragma unroll
                for (int r = 0; r < 4; ++r) o_acc[ti][dj][r] *= alpha[ti][r];

        __syncthreads();
#pragma unroll
        for (int l = 0; l < 4; ++l) {
            int idx = l * 256 + t;
            int d = idx >> 4, kc = (idx & 15) * 8;
            *(bf16x8*)(KV + d * 136 + kc) =
                *(const bf16x8*)(Vt + ((size_t)(b * 16 + h) * 64 + d) * 2048 + jb + kc);
        }
        __syncthreads();
#pragma unroll
        for (int ks = 0; ks < 4; ++ks) {
            bf16x8 ap[2], bv8[4];
#pragma unroll
            for (int ti = 0; ti < 2; ++ti)
                ap[ti] = *(bf16x8*)(PsQ + (wave * 32 + ti * 16 + l16) * 136 + ks * 32 + quad * 8);
#pragma unroll
            for (int dj = 0; dj < 4; ++dj)
                bv8[dj] = *(bf16x8*)(KV + (dj * 16 + l16) * 136 + ks * 32 + quad * 8);
#pragma unroll
            for (int ti = 0; ti < 2; ++ti)
#pragma unroll
                for (int dj = 0; dj < 4; ++dj)
                    o_acc[ti][dj] = mfma16(ap[ti], bv8[dj], o_acc[ti][dj]);
        }
    }

#pragma unroll
    for (int ti = 0; ti < 2; ++ti) {
        int irow_base = q0 + wave * 32 + ti * 16 + quad * 4;
#pragma unroll
        for (int r = 0; r < 4; ++r) {
            int i = irow_base + r;
            float m2 = fmaxf(m_run[ti][r], s_g[ti][r]);
            float pg = safe_exp(s_g[ti][r] - m2);
            float al = safe_exp(m_run[ti][r] - m2);
            float l2 = l_run[ti][r] * al + pg;
            float invl = 1.f / fmaxf(l2, 1e-30f);
            float qm = (mask[bs_off + i] > 0) ? 0.f : 1.f;
#pragma unroll
            for (int dj = 0; dj < 4; ++dj) {
                int d = dj * 16 + l16;
                float val = (o_acc[ti][dj][r] * al + pg * gvf[d]) * invl * qm;
                attn[((size_t)(bs_off + i)) * 1024 + h * 64 + d] = f2b(val);
            }
        }
    }
}

// ---------------------------------------------------------------------------
// y = LN(x + attn) * g + b ; writes bf16 (GEMM input) AND fp32 (residual).
// ---------------------------------------------------------------------------
__global__ __launch_bounds__(256) void resid_ln(
    const float* __restrict__ x, const short* __restrict__ attn,
    const float* __restrict__ g, const float* __restrict__ be,
    short* __restrict__ yb, float* __restrict__ yf)
{
    int row = blockIdx.x, t = threadIdx.x;
    int lane = t & 63, wave = t >> 6;
    const size_t base = (size_t)row * 1024;
    float v[4]; float s = 0.f, s2 = 0.f;
#pragma unroll
    for (int i = 0; i < 4; ++i) {
        int c = i * 256 + t;
        float val = x[base + c] + b2f(attn[base + c]);
        v[i] = val; s += val; s2 += val * val;
    }
#pragma unroll
    for (int off = 32; off > 0; off >>= 1) { s += __shfl_xor(s, off); s2 += __shfl_xor(s2, off); }
    __shared__ float red[8];
    if (lane == 0) { red[wave] = s; red[4 + wave] = s2; }
    __syncthreads();
    s  = red[0] + red[1] + red[2] + red[3];
    s2 = red[4] + red[5] + red[6] + red[7];
    float mu  = s * (1.f / 1024.f);
    float var = s2 * (1.f / 1024.f) - mu * mu;
    float inv = rsqrtf(fmaxf(var, 0.f) + 1e-5f);
#pragma unroll
    for (int i = 0; i < 4; ++i) {
        int c = i * 256 + t;
        float o = (v[i] - mu) * inv * g[c] + be[c];
        yb[base + c] = f2b(o);
        yf[base + c] = o;
    }
}

// ---------------------------------------------------------------------------
// workspace layout, units = bf16 elements (2 B). total 47M units = 94 MB.
// ---------------------------------------------------------------------------
static constexpr size_t MEG      = 1048576;
static constexpr size_t OFF_WQKV = 0;            // 3M  (3072x1024 bf16)
static constexpr size_t OFF_W1T  = 3 * MEG;      // 4M
static constexpr size_t OFF_W2T  = 7 * MEG;      // 4M
static constexpr size_t OFF_XB   = 11 * MEG;     // 4M
static constexpr size_t OFF_QKV  = 15 * MEG;     // 12M (4096x3072 bf16; V third unused)
static constexpr size_t OFF_VT   = 27 * MEG;     // 4M
static constexpr size_t OFF_ATT  = 31 * MEG;     // 4M
static constexpr size_t OFF_YN   = 35 * MEG;     // 4M (bf16)
static constexpr size_t OFF_YF   = 39 * MEG;     // 8M units = 4M fp32
static constexpr size_t OFF_H    = OFF_QKV;      // 16M, aliases QKV+VT (dead)

extern "C" void kernel_launch(void* const* d_in, const int* in_sizes, int n_in,
                              void* d_out, int out_size, void* d_ws, size_t ws_size,
                              hipStream_t stream) {
    (void)in_sizes; (void)n_in; (void)out_size; (void)ws_size;
    const float* x    = (const float*)d_in[0];
    const int*   mask = (const int*)  d_in[1];
    const float* wq   = (const float*)d_in[2];
    const float* bq   = (const float*)d_in[3];
    const float* wk   = (const float*)d_in[4];
    const float* bk   = (const float*)d_in[5];
    const float* wv   = (const float*)d_in[6];
    const float* bv   = (const float*)d_in[7];
    // d_in[8..13] (global-query branch) are provably dead for the output
    const float* lng  = (const float*)d_in[14];
    const float* lnb  = (const float*)d_in[15];
    const float* w1   = (const float*)d_in[16];
    const float* b1   = (const float*)d_in[17];
    const float* w2   = (const float*)d_in[18];
    const float* b2   = (const float*)d_in[19];
    short* ws  = (short*)d_ws;
    float* out = (float*)d_out;

    dim3 tb(32, 8);
    cvt_transpose_qkv<<<dim3(32, 32, 3), tb, 0, stream>>>(wq, wk, wv, ws + OFF_WQKV);
    cvt_transpose<<<dim3(128, 32), tb, 0, stream>>>(w1, ws + OFF_W1T, 1024, 4096);
    cvt_transpose<<<dim3(32, 128), tb, 0, stream>>>(w2, ws + OFF_W2T, 4096, 1024);
    cvt_f32_bf16<<<4096, 256, 0, stream>>>(x, ws + OFF_XB, 4194304);

    // QKV = x @ [wq|wk|wv] + [bq|bk|bv]; Q scaled 1/8; V staged -> Vt fused
    gemm_bt<<<dim3(32, 24), 256, 0, stream>>>(ws + OFF_XB, ws + OFF_WQKV,
                                              bq, bk, bv,
                                              ws + OFF_QKV, ws + OFF_VT,
                                              4096, 3072, 1024, 0.125f, 0);

    attn_kernel<<<512, 256, 53760, stream>>>(ws + OFF_QKV, ws + OFF_VT,
                                             mask, bk, bv, ws + OFF_ATT);

    resid_ln<<<4096, 256, 0, stream>>>(x, ws + OFF_ATT, lng, lnb,
                                       ws + OFF_YN, (float*)(ws + OFF_YF));

    // h = gelu(y@w1 + b1)
    gemm_bt<<<dim3(32, 32), 256, 0, stream>>>(ws + OFF_YN, ws + OFF_W1T,
                                              b1, nullptr, nullptr,
                                              ws + OFF_H, nullptr,
                                              4096, 4096, 1024, 1.0f, 1);
    // out = y + h@w2 + b2 (64^2 tile, double-buffered, counted vmcnt,
    // natural block order)
    gemm64_db<<<dim3(64, 16), 256, 0, stream>>>(ws + OFF_H, ws + OFF_W2T,
                                                b2, (const float*)(ws + OFF_YF),
                                                out, 4096, 1024, 4096);
}

// Round 7
// 336.067 us; speedup vs baseline: 1.0846x; 1.0102x over previous
//
#include <hip/hip_runtime.h>

// ---------------------------------------------------------------------------
// HFLongFormerSelfAttentionBlock — MI355X implementation (round 13)
//
// I/O fp32; internal bf16 MFMA, fp32 accumulation/epilogues.
// Round-13:
//  * gemm_bt XCD swizzle REVERTED (same disease as gemm64_db in r5: remap
//    gave each XCD the full A matrix through its 4 MB L2; natural order
//    partitions A m%8 -> L2-fit).
//  * MLP2: 64^2 tile was LDS-BW-bound (r6: FETCH fixed at 58 MB, dur stuck
//    at 59us; 3.15 GB LDS traffic / 256 CU / ~100 B/cyc ~= the measured
//    floor). New gemm128x64_db: 128x64 tile, wave owns 64x32 (acc[4][2]) ->
//    FLOP per LDS byte 16 -> 21.8, traffic -25%. Grid (32,16)=512, 48 KB
//    LDS dbuf (2-3 blocks/CU), counted vmcnt(6) pipeline.
// ---------------------------------------------------------------------------

using bf16x8 = __attribute__((ext_vector_type(8))) short;
using bf16x4 = __attribute__((ext_vector_type(4))) short;
using f32x4  = __attribute__((ext_vector_type(4))) float;

__device__ __forceinline__ float b2f(short s) {
    return __uint_as_float(((unsigned int)(unsigned short)s) << 16);
}
__device__ __forceinline__ short f2b(float f) {
    unsigned int u = __float_as_uint(f);
    u += 0x7fffu + ((u >> 16) & 1u);   // round-to-nearest-even
    return (short)(u >> 16);
}
__device__ __forceinline__ f32x4 mfma16(bf16x8 a, bf16x8 b, f32x4 c) {
    return __builtin_amdgcn_mfma_f32_16x16x32_bf16(a, b, c, 0, 0, 0);
}
__device__ __forceinline__ float safe_exp(float x) {
    return expf((x <= 0.f) ? x : 0.f);
}
// gelu(v) = 0.5 v (1 + erf(v/sqrt2)); erf via A&S 7.1.25 (|err| <= 2.5e-5,
// branch-free: rcp + exp + 5 fma). 100x below bf16 output quantization.
__device__ __forceinline__ float fast_gelu(float v) {
    float z  = fabsf(v) * 0.70710678118f;
    float t  = __builtin_amdgcn_rcpf(fmaf(0.47047f, z, 1.f));
    float e  = __expf(-z * z);
    float p  = t * fmaf(t, fmaf(t, 0.7478556f, -0.0958798f), 0.3480242f);
    float er = fmaf(-p, e, 1.f);                  // erf(|z|)
    er = (v < 0.f) ? -er : er;
    return 0.5f * v * (1.f + er);
}
// async global->LDS, 16 B per lane; LDS dest = wave-uniform base + lane*16
__device__ __forceinline__ void load_lds16(const short* g, short* l) {
    __builtin_amdgcn_global_load_lds((const __attribute__((address_space(1))) void*)g,
                                     (__attribute__((address_space(3))) void*)l, 16, 0, 0);
}
#define NEGF (-3.0e38f)

// ---------------------------------------------------------------------------
// fp32 -> bf16 elementwise convert (n multiple of 1024). grid n/1024, 256 thr
// ---------------------------------------------------------------------------
__global__ void cvt_f32_bf16(const float* __restrict__ in, short* __restrict__ out, int n) {
    int i = (blockIdx.x * 256 + threadIdx.x) * 4;
    f32x4 v = *(const f32x4*)(in + i);
    bf16x4 o;
#pragma unroll
    for (int j = 0; j < 4; ++j) o[j] = f2b(v[j]);
    *(bf16x4*)(out + i) = o;
}

// ---------------------------------------------------------------------------
// fp32 in, bf16 transposed out: out[c][r] = in[r][c], in is R x C.
// grid (C/32, R/32), block (32,8)
// ---------------------------------------------------------------------------
__global__ void cvt_transpose(const float* __restrict__ in, short* __restrict__ out,
                              int R, int C) {
    __shared__ short tile[32][33];
    int bx = blockIdx.x * 32, by = blockIdx.y * 32;
    int tx = threadIdx.x, ty = threadIdx.y;
    for (int i = ty; i < 32; i += 8)
        tile[i][tx] = f2b(in[(size_t)(by + i) * C + bx + tx]);
    __syncthreads();
    for (int i = ty; i < 32; i += 8)
        out[(size_t)(bx + i) * R + by + tx] = tile[tx][i];
}

// wq/wk/wv (each 1024x1024 fp32) -> WQKVT (3072x1024 bf16, = [wq^T;wk^T;wv^T])
__global__ void cvt_transpose_qkv(const float* __restrict__ wq, const float* __restrict__ wk,
                                  const float* __restrict__ wv, short* __restrict__ out) {
    __shared__ short tile[32][33];
    const float* in = (blockIdx.z == 0) ? wq : (blockIdx.z == 1) ? wk : wv;
    short* dst = out + (size_t)blockIdx.z * 1024 * 1024;
    int bx = blockIdx.x * 32, by = blockIdx.y * 32;
    int tx = threadIdx.x, ty = threadIdx.y;
    for (int i = ty; i < 32; i += 8)
        tile[i][tx] = f2b(in[(size_t)(by + i) * 1024 + bx + tx]);
    __syncthreads();
    for (int i = ty; i < 32; i += 8)
        dst[(size_t)(bx + i) * 1024 + by + tx] = tile[tx][i];
}

// ---------------------------------------------------------------------------
// GEMM 128x128, BK=64, XOR-swizzled LDS k-chunks. NATURAL block order.
// mode 0: QKV — bias by col segment, Q scaled, V staged+transposed -> Vt
// mode 1: C = bf16(gelu(acc + bias0[col]))
// Epilogue always stages the tile in LDS, then coalesced 16-B stores.
// ---------------------------------------------------------------------------
__global__ __launch_bounds__(256, 4) void gemm_bt(
    const short* __restrict__ A, const short* __restrict__ Bt,
    const float* __restrict__ bias0, const float* __restrict__ bias1,
    const float* __restrict__ bias2,
    short* __restrict__ C, short* __restrict__ Vt,
    int M, int N, int K, float scale, int mode)
{
    __shared__ short sh[128 * 136];   // 34.8 KB; main loop uses first 16K shorts
    short* As = sh;
    short* Bs = sh + 8192;
    int m0 = blockIdx.x * 128, n0 = blockIdx.y * 128;
    int t = threadIdx.x;
    int wave = t >> 6, lane = t & 63, quad = lane >> 4, l16 = lane & 15;
    int wr = (wave >> 1) * 64, wc = (wave & 1) * 64;

    // staging pointers: 4 chunks per wave per buffer
    const short* ap[4]; const short* bp[4]; short* la[4]; short* lb[4];
    int gk = (((lane & 7) ^ (lane >> 3)) * 8);
#pragma unroll
    for (int l = 0; l < 4; ++l) {
        int c = wave * 4 + l;
        int row = c * 8 + (lane >> 3);
        ap[l] = A  + (size_t)(m0 + row) * K + gk;
        bp[l] = Bt + (size_t)(n0 + row) * K + gk;
        la[l] = As + c * 512;
        lb[l] = Bs + c * 512;
    }
    int sw = l16 & 7;   // frag-read swizzle key

    f32x4 acc[4][4] = {};
    for (int k0 = 0; k0 < K; k0 += 64) {
#pragma unroll
        for (int l = 0; l < 4; ++l) { load_lds16(ap[l] + k0, la[l]); load_lds16(bp[l] + k0, lb[l]); }
        __syncthreads();
#pragma unroll
        for (int ks = 0; ks < 2; ++ks) {
            int slot = ((ks * 4 + quad) ^ sw) * 8;
            bf16x8 af[4], bfr[4];
#pragma unroll
            for (int i = 0; i < 4; ++i)
                af[i] = *(bf16x8*)(As + (wr + i * 16 + l16) * 64 + slot);
#pragma unroll
            for (int j = 0; j < 4; ++j)
                bfr[j] = *(bf16x8*)(Bs + (wc + j * 16 + l16) * 64 + slot);
#pragma unroll
            for (int i = 0; i < 4; ++i)
#pragma unroll
                for (int j = 0; j < 4; ++j)
                    acc[i][j] = mfma16(af[i], bfr[j], acc[i][j]);
        }
        __syncthreads();
    }
    // after final barrier, all LDS reads are done -> sh reusable for staging

    int seg0 = n0 >> 10;   // tiles are 128-aligned: never straddle a segment
    if (mode == 1 || seg0 < 2) {
        // ---- stage bf16 tile in LDS: sh[row*136 + col], row/col in [0,128)
        if (mode == 1) {
#pragma unroll
            for (int j = 0; j < 4; ++j) {
                int col = n0 + wc + j * 16 + l16;
                float bs = bias0[col];
#pragma unroll
                for (int i = 0; i < 4; ++i)
#pragma unroll
                    for (int r = 0; r < 4; ++r) {
                        float v = fast_gelu(acc[i][j][r] + bs);
                        sh[(wr + i * 16 + quad * 4 + r) * 136 + wc + j * 16 + l16] = f2b(v);
                    }
            }
        } else {
            float sc = (seg0 == 0) ? scale : 1.0f;
            const float* bpt = (seg0 == 0) ? bias0 : bias1;
#pragma unroll
            for (int j = 0; j < 4; ++j) {
                int col = n0 + wc + j * 16 + l16;
                float bs = bpt[col & 1023];
#pragma unroll
                for (int i = 0; i < 4; ++i)
#pragma unroll
                    for (int r = 0; r < 4; ++r)
                        sh[(wr + i * 16 + quad * 4 + r) * 136 + wc + j * 16 + l16] =
                            f2b((acc[i][j][r] + bs) * sc);
            }
        }
        __syncthreads();
        // ---- coalesced write-out: 2 threads per row, 8 x 16 B each
        int row = t >> 1, half = t & 1;
        const short* src = sh + row * 136 + half * 64;
        short* dst = C + (size_t)(m0 + row) * N + n0 + half * 64;
#pragma unroll
        for (int cgk = 0; cgk < 8; ++cgk)
            *(bf16x8*)(dst + cgk * 8) = *(const bf16x8*)(src + cgk * 8);
    } else {
        // ---- V part: stage TRANSPOSED in LDS (sh[c*136 + row]), then write
        //      Vt (b, h, d, s) with 16-B chunks coalesced along s.
#pragma unroll
        for (int j = 0; j < 4; ++j) {
            int cl = wc + j * 16 + l16;                 // local col in [0,128)
            float bs = bias2[(n0 & 1023) + cl];
#pragma unroll
            for (int i = 0; i < 4; ++i)
#pragma unroll
                for (int r = 0; r < 4; ++r)
                    sh[cl * 136 + wr + i * 16 + quad * 4 + r] = f2b(acc[i][j][r] + bs);
        }
        __syncthreads();
        int h0 = (n0 & 1023) >> 6;                      // first head of tile
        int bb = m0 >> 11, s0 = m0 & 2047;
        int sc = t & 15;                                // s-chunk within tile
#pragma unroll
        for (int cgk = 0; cgk < 8; ++cgk) {
            int cl = (t >> 4) + cgk * 16;               // local col
            int h = h0 + (cl >> 6), d = cl & 63;
            *(bf16x8*)(Vt + (((size_t)(bb * 16 + h)) * 64 + d) * 2048 + s0 + sc * 8) =
                *(const bf16x8*)(sh + cl * 136 + sc * 8);
        }
    }
}

// ---------------------------------------------------------------------------
// MLP2 GEMM: 128x64 tile, BK=64, wave owns 64x32 (acc[4][2]) — FLOP per LDS
// byte 21.8 vs 16 at 64^2 (the 64^2 kernel was LDS-BW-bound: 3.15 GB LDS
// traffic ~= its 59us). Double-buffered, counted vmcnt(6) (4A+2B loads per
// wave per tile). Natural block order (A partitioned m%8 across XCD L2s).
// Cf = A@B + bias + resf (fp32 out). grid (M/128, N/64), 256 thr, 48 KB LDS.
// ---------------------------------------------------------------------------
__global__ __launch_bounds__(256, 2) void gemm128x64_db(
    const short* __restrict__ A, const short* __restrict__ Bt,
    const float* __restrict__ bias, const float* __restrict__ resf,
    float* __restrict__ Cf, int M, int N, int K)
{
    __shared__ short As[2][128 * 64];
    __shared__ short Bs[2][64 * 64];
    int m0 = blockIdx.x * 128, n0 = blockIdx.y * 64;
    int t = threadIdx.x;
    int wave = t >> 6, lane = t & 63, quad = lane >> 4, l16 = lane & 15;
    int wr = (wave >> 1) * 64, wc = (wave & 1) * 32;

    const short* ap[4]; const short* bp[2]; int loA[4], loB[2];
    int gk = (((lane & 7) ^ (lane >> 3)) * 8);
#pragma unroll
    for (int l = 0; l < 4; ++l) {
        int c = wave * 4 + l;                 // A-chunks 0..15
        int row = c * 8 + (lane >> 3);
        ap[l] = A + (size_t)(m0 + row) * K + gk;
        loA[l] = c * 512;
    }
#pragma unroll
    for (int l = 0; l < 2; ++l) {
        int c = wave * 2 + l;                 // B-chunks 0..7
        int row = c * 8 + (lane >> 3);
        bp[l] = Bt + (size_t)(n0 + row) * K + gk;
        loB[l] = c * 512;
    }
    int sw = l16 & 7;

    const int nt = K >> 6;
    // prologue: stage tile 0
#pragma unroll
    for (int l = 0; l < 4; ++l) load_lds16(ap[l], &As[0][loA[l]]);
#pragma unroll
    for (int l = 0; l < 2; ++l) load_lds16(bp[l], &Bs[0][loB[l]]);

    f32x4 acc[4][2] = {};
    for (int ti = 0; ti < nt; ++ti) {
        int cur = ti & 1;
        if (ti + 1 < nt) {
            int k0 = (ti + 1) << 6;
#pragma unroll
            for (int l = 0; l < 4; ++l) load_lds16(ap[l] + k0, &As[cur ^ 1][loA[l]]);
#pragma unroll
            for (int l = 0; l < 2; ++l) load_lds16(bp[l] + k0, &Bs[cur ^ 1][loB[l]]);
            asm volatile("s_waitcnt vmcnt(6)" ::: "memory");  // drain cur's 6 only
        } else {
            asm volatile("s_waitcnt vmcnt(0)" ::: "memory");
        }
        __builtin_amdgcn_s_barrier();
        asm volatile("" ::: "memory");

        const short* as = &As[cur][0];
        const short* bs = &Bs[cur][0];
#pragma unroll
        for (int ks = 0; ks < 2; ++ks) {
            int slot = ((ks * 4 + quad) ^ sw) * 8;
            bf16x8 af[4], bfr[2];
#pragma unroll
            for (int i = 0; i < 4; ++i)
                af[i] = *(bf16x8*)(as + (wr + i * 16 + l16) * 64 + slot);
#pragma unroll
            for (int j = 0; j < 2; ++j)
                bfr[j] = *(bf16x8*)(bs + (wc + j * 16 + l16) * 64 + slot);
#pragma unroll
            for (int i = 0; i < 4; ++i)
#pragma unroll
                for (int j = 0; j < 2; ++j)
                    acc[i][j] = mfma16(af[i], bfr[j], acc[i][j]);
        }
        asm volatile("" ::: "memory");
        __builtin_amdgcn_s_barrier();   // protect buf cur^1 before next stage
    }

#pragma unroll
    for (int j = 0; j < 2; ++j) {
        int col = n0 + wc + j * 16 + l16;
        float bs = bias[col];
#pragma unroll
        for (int i = 0; i < 4; ++i) {
#pragma unroll
            for (int r = 0; r < 4; ++r) {
                int row = m0 + wr + i * 16 + quad * 4 + r;
                Cf[(size_t)row * N + col] = acc[i][j][r] + bs + resf[(size_t)row * N + col];
            }
        }
    }
}

// ---------------------------------------------------------------------------
// Windowed attention with global column (structure unchanged since round 4).
// ---------------------------------------------------------------------------
__global__ __launch_bounds__(256, 2) void attn_kernel(
    const short* __restrict__ QKV, const short* __restrict__ Vt,
    const int* __restrict__ mask,
    const float* __restrict__ bk, const float* __restrict__ bv,
    short* __restrict__ attn)
{
    extern __shared__ char smem[];
    short* PsQ = (short*)smem;
    short* KV  = (short*)(smem + 34816);
    float* gkf = (float*)(smem + 53248);
    float* gvf = (float*)(smem + 53504);

    int blk = blockIdx.x;
    int c = blk & 15, h = (blk >> 4) & 15, b = blk >> 8;
    int t = threadIdx.x;
    int wave = t >> 6, lane = t & 63, quad = lane >> 4, l16 = lane & 15;
    int q0 = c * 128;
    const int bs_off = b * 2048;
    const short* Q = QKV + h * 64;
    const short* K = QKV + 1024 + h * 64;

#pragma unroll
    for (int l = 0; l < 4; ++l) {
        int idx = l * 256 + t;
        int p = idx >> 3, dc = (idx & 7) * 8;
        *(bf16x8*)(PsQ + p * 72 + dc) =
            *(const bf16x8*)(Q + ((size_t)(bs_off + q0 + p)) * 3072 + dc);
    }
    if (t < 64) { gkf[t] = bk[h * 64 + t]; gvf[t] = bv[h * 64 + t]; }
    __syncthreads();

    bf16x8 aq[2][2];
#pragma unroll
    for (int ti = 0; ti < 2; ++ti)
#pragma unroll
        for (int ks = 0; ks < 2; ++ks)
            aq[ti][ks] = *(bf16x8*)(PsQ + (wave * 32 + ti * 16 + l16) * 72 + ks * 32 + quad * 8);

    float s_g[2][4];
#pragma unroll
    for (int ti = 0; ti < 2; ++ti)
#pragma unroll
        for (int r = 0; r < 4; ++r) {
            int row = wave * 32 + ti * 16 + quad * 4 + r;
            float part = 0.f;
#pragma unroll
            for (int dd = 0; dd < 4; ++dd) {
                int d = l16 * 4 + dd;
                part += b2f(PsQ[row * 72 + d]) * gkf[d];
            }
#pragma unroll
            for (int dsh = 1; dsh < 16; dsh <<= 1) part += __shfl_xor(part, dsh);
            s_g[ti][r] = part;
        }

    f32x4 o_acc[2][4] = {};
    float m_run[2][4], l_run[2][4];
#pragma unroll
    for (int ti = 0; ti < 2; ++ti)
#pragma unroll
        for (int r = 0; r < 4; ++r) { m_run[ti][r] = NEGF; l_run[ti][r] = 0.f; }

    int kt_beg = (q0 == 0) ? 1 : 0;
    int kt_end = (q0 + 256 > 2048) ? 2 : 3;
    for (int kt = kt_beg; kt < kt_end; ++kt) {
        int jb = q0 + (kt - 1) * 128;
        __syncthreads();
#pragma unroll
        for (int l = 0; l < 4; ++l) {
            int idx = l * 256 + t;
            int p = idx >> 3, dc = (idx & 7) * 8;
            *(bf16x8*)(KV + p * 72 + dc) =
                *(const bf16x8*)(K + ((size_t)(bs_off + jb + p)) * 3072 + dc);
        }
        __syncthreads();

        f32x4 s_acc[2][8] = {};
#pragma unroll
        for (int ks = 0; ks < 2; ++ks) {
            bf16x8 bk8[8];
#pragma unroll
            for (int tj = 0; tj < 8; ++tj)
                bk8[tj] = *(bf16x8*)(KV + (tj * 16 + l16) * 72 + ks * 32 + quad * 8);
#pragma unroll
            for (int ti = 0; ti < 2; ++ti)
#pragma unroll
                for (int tj = 0; tj < 8; ++tj)
                    s_acc[ti][tj] = mfma16(aq[ti][ks], bk8[tj], s_acc[ti][tj]);
        }

        float negj[8]; int jcol[8];
#pragma unroll
        for (int tj = 0; tj < 8; ++tj) {
            jcol[tj] = jb + tj * 16 + l16;
            negj[tj] = (mask[bs_off + jcol[tj]] != 0) ? NEGF : 0.f;
        }
        float tmax[2][4];
#pragma unroll
        for (int ti = 0; ti < 2; ++ti)
#pragma unroll
            for (int r = 0; r < 4; ++r) tmax[ti][r] = NEGF;
#pragma unroll
        for (int ti = 0; ti < 2; ++ti) {
            int irow_base = q0 + wave * 32 + ti * 16 + quad * 4;
#pragma unroll
            for (int tj = 0; tj < 8; ++tj)
#pragma unroll
                for (int r = 0; r < 4; ++r) {
                    int dj = jcol[tj] - (irow_base + r);
                    float sc = (dj >= -128 && dj <= 128) ? (s_acc[ti][tj][r] + negj[tj]) : NEGF;
                    s_acc[ti][tj][r] = sc;
                    tmax[ti][r] = fmaxf(tmax[ti][r], sc);
                }
        }
#pragma unroll
        for (int ti = 0; ti < 2; ++ti)
#pragma unroll
            for (int r = 0; r < 4; ++r)
#pragma unroll
                for (int dsh = 1; dsh < 16; dsh <<= 1)
                    tmax[ti][r] = fmaxf(tmax[ti][r], __shfl_xor(tmax[ti][r], dsh));

        float alpha[2][4], lsum[2][4];
#pragma unroll
        for (int ti = 0; ti < 2; ++ti)
#pragma unroll
            for (int r = 0; r < 4; ++r) {
                float mnew = fmaxf(m_run[ti][r], tmax[ti][r]);
                alpha[ti][r] = safe_exp(m_run[ti][r] - mnew);
                m_run[ti][r] = mnew;
                lsum[ti][r] = 0.f;
            }
#pragma unroll
        for (int ti = 0; ti < 2; ++ti)
#pragma unroll
            for (int tj = 0; tj < 8; ++tj)
#pragma unroll
                for (int r = 0; r < 4; ++r) {
                    float p = safe_exp(s_acc[ti][tj][r] - m_run[ti][r]);
                    lsum[ti][r] += p;
                    PsQ[(wave * 32 + ti * 16 + quad * 4 + r) * 136 + tj * 16 + l16] = f2b(p);
                }
#pragma unroll
        for (int ti = 0; ti < 2; ++ti)
#pragma unroll
            for (int r = 0; r < 4; ++r) {
#pragma unroll
                for (int dsh = 1; dsh < 16; dsh <<= 1) lsum[ti][r] += __shfl_xor(lsum[ti][r], dsh);
                l_run[ti][r] = l_run[ti][r] * alpha[ti][r] + lsum[ti][r];
            }
#pragma unroll
        for (int ti = 0; ti < 2; ++ti)
#pragma unroll
            for (int dj = 0; dj < 4; ++dj)
#pragma unroll
                for (int r = 0; r < 4; ++r) o_acc[ti][dj][r] *= alpha[ti][r];

        __syncthreads();
#pragma unroll
        for (int l = 0; l < 4; ++l) {
            int idx = l * 256 + t;
            int d = idx >> 4, kc = (idx & 15) * 8;
            *(bf16x8*)(KV + d * 136 + kc) =
                *(const bf16x8*)(Vt + ((size_t)(b * 16 + h) * 64 + d) * 2048 + jb + kc);
        }
        __syncthreads();
#pragma unroll
        for (int ks = 0; ks < 4; ++ks) {
            bf16x8 ap[2], bv8[4];
#pragma unroll
            for (int ti = 0; ti < 2; ++ti)
                ap[ti] = *(bf16x8*)(PsQ + (wave * 32 + ti * 16 + l16) * 136 + ks * 32 + quad * 8);
#pragma unroll
            for (int dj = 0; dj < 4; ++dj)
                bv8[dj] = *(bf16x8*)(KV + (dj * 16 + l16) * 136 + ks * 32 + quad * 8);
#pragma unroll
            for (int ti = 0; ti < 2; ++ti)
#pragma unroll
                for (int dj = 0; dj < 4; ++dj)
                    o_acc[ti][dj] = mfma16(ap[ti], bv8[dj], o_acc[ti][dj]);
        }
    }

#pragma unroll
    for (int ti = 0; ti < 2; ++ti) {
        int irow_base = q0 + wave * 32 + ti * 16 + quad * 4;
#pragma unroll
        for (int r = 0; r < 4; ++r) {
            int i = irow_base + r;
            float m2 = fmaxf(m_run[ti][r], s_g[ti][r]);
            float pg = safe_exp(s_g[ti][r] - m2);
            float al = safe_exp(m_run[ti][r] - m2);
            float l2 = l_run[ti][r] * al + pg;
            float invl = 1.f / fmaxf(l2, 1e-30f);
            float qm = (mask[bs_off + i] > 0) ? 0.f : 1.f;
#pragma unroll
            for (int dj = 0; dj < 4; ++dj) {
                int d = dj * 16 + l16;
                float val = (o_acc[ti][dj][r] * al + pg * gvf[d]) * invl * qm;
                attn[((size_t)(bs_off + i)) * 1024 + h * 64 + d] = f2b(val);
            }
        }
    }
}

// ---------------------------------------------------------------------------
// y = LN(x + attn) * g + b ; writes bf16 (GEMM input) AND fp32 (residual).
// ---------------------------------------------------------------------------
__global__ __launch_bounds__(256) void resid_ln(
    const float* __restrict__ x, const short* __restrict__ attn,
    const float* __restrict__ g, const float* __restrict__ be,
    short* __restrict__ yb, float* __restrict__ yf)
{
    int row = blockIdx.x, t = threadIdx.x;
    int lane = t & 63, wave = t >> 6;
    const size_t base = (size_t)row * 1024;
    float v[4]; float s = 0.f, s2 = 0.f;
#pragma unroll
    for (int i = 0; i < 4; ++i) {
        int c = i * 256 + t;
        float val = x[base + c] + b2f(attn[base + c]);
        v[i] = val; s += val; s2 += val * val;
    }
#pragma unroll
    for (int off = 32; off > 0; off >>= 1) { s += __shfl_xor(s, off); s2 += __shfl_xor(s2, off); }
    __shared__ float red[8];
    if (lane == 0) { red[wave] = s; red[4 + wave] = s2; }
    __syncthreads();
    s  = red[0] + red[1] + red[2] + red[3];
    s2 = red[4] + red[5] + red[6] + red[7];
    float mu  = s * (1.f / 1024.f);
    float var = s2 * (1.f / 1024.f) - mu * mu;
    float inv = rsqrtf(fmaxf(var, 0.f) + 1e-5f);
#pragma unroll
    for (int i = 0; i < 4; ++i) {
        int c = i * 256 + t;
        float o = (v[i] - mu) * inv * g[c] + be[c];
        yb[base + c] = f2b(o);
        yf[base + c] = o;
    }
}

// ---------------------------------------------------------------------------
// workspace layout, units = bf16 elements (2 B). total 47M units = 94 MB.
// ---------------------------------------------------------------------------
static constexpr size_t MEG      = 1048576;
static constexpr size_t OFF_WQKV = 0;            // 3M  (3072x1024 bf16)
static constexpr size_t OFF_W1T  = 3 * MEG;      // 4M
static constexpr size_t OFF_W2T  = 7 * MEG;      // 4M
static constexpr size_t OFF_XB   = 11 * MEG;     // 4M
static constexpr size_t OFF_QKV  = 15 * MEG;     // 12M (4096x3072 bf16; V third unused)
static constexpr size_t OFF_VT   = 27 * MEG;     // 4M
static constexpr size_t OFF_ATT  = 31 * MEG;     // 4M
static constexpr size_t OFF_YN   = 35 * MEG;     // 4M (bf16)
static constexpr size_t OFF_YF   = 39 * MEG;     // 8M units = 4M fp32
static constexpr size_t OFF_H    = OFF_QKV;      // 16M, aliases QKV+VT (dead)

extern "C" void kernel_launch(void* const* d_in, const int* in_sizes, int n_in,
                              void* d_out, int out_size, void* d_ws, size_t ws_size,
                              hipStream_t stream) {
    (void)in_sizes; (void)n_in; (void)out_size; (void)ws_size;
    const float* x    = (const float*)d_in[0];
    const int*   mask = (const int*)  d_in[1];
    const float* wq   = (const float*)d_in[2];
    const float* bq   = (const float*)d_in[3];
    const float* wk   = (const float*)d_in[4];
    const float* bk   = (const float*)d_in[5];
    const float* wv   = (const float*)d_in[6];
    const float* bv   = (const float*)d_in[7];
    // d_in[8..13] (global-query branch) are provably dead for the output
    const float* lng  = (const float*)d_in[14];
    const float* lnb  = (const float*)d_in[15];
    const float* w1   = (const float*)d_in[16];
    const float* b1   = (const float*)d_in[17];
    const float* w2   = (const float*)d_in[18];
    const float* b2   = (const float*)d_in[19];
    short* ws  = (short*)d_ws;
    float* out = (float*)d_out;

    dim3 tb(32, 8);
    cvt_transpose_qkv<<<dim3(32, 32, 3), tb, 0, stream>>>(wq, wk, wv, ws + OFF_WQKV);
    cvt_transpose<<<dim3(128, 32), tb, 0, stream>>>(w1, ws + OFF_W1T, 1024, 4096);
    cvt_transpose<<<dim3(32, 128), tb, 0, stream>>>(w2, ws + OFF_W2T, 4096, 1024);
    cvt_f32_bf16<<<4096, 256, 0, stream>>>(x, ws + OFF_XB, 4194304);

    // QKV = x @ [wq|wk|wv] + [bq|bk|bv]; Q scaled 1/8; V staged -> Vt fused
    gemm_bt<<<dim3(32, 24), 256, 0, stream>>>(ws + OFF_XB, ws + OFF_WQKV,
                                              bq, bk, bv,
                                              ws + OFF_QKV, ws + OFF_VT,
                                              4096, 3072, 1024, 0.125f, 0);

    attn_kernel<<<512, 256, 53760, stream>>>(ws + OFF_QKV, ws + OFF_VT,
                                             mask, bk, bv, ws + OFF_ATT);

    resid_ln<<<4096, 256, 0, stream>>>(x, ws + OFF_ATT, lng, lnb,
                                       ws + OFF_YN, (float*)(ws + OFF_YF));

    // h = gelu(y@w1 + b1)
    gemm_bt<<<dim3(32, 32), 256, 0, stream>>>(ws + OFF_YN, ws + OFF_W1T,
                                              b1, nullptr, nullptr,
                                              ws + OFF_H, nullptr,
                                              4096, 4096, 1024, 1.0f, 1);
    // out = y + h@w2 + b2 (128x64 tile, wave=64x32, dbuf + counted vmcnt(6))
    gemm128x64_db<<<dim3(32, 16), 256, 0, stream>>>(ws + OFF_H, ws + OFF_W2T,
                                                    b2, (const float*)(ws + OFF_YF),
                                                    out, 4096, 1024, 4096);
}

// Round 8
// 316.038 us; speedup vs baseline: 1.1533x; 1.0634x over previous
//
#include <hip/hip_runtime.h>

// ---------------------------------------------------------------------------
// HFLongFormerSelfAttentionBlock — MI355X implementation (round 14)
//
// I/O fp32; internal bf16 MFMA, fp32 accumulation/epilogues.
// Round-14: attention is now the top dispatch (68us, MfmaUtil 3%, VALU 27%,
// Occ 20% -> ~85% stall). Two changes:
//  1. T14 async-STAGE split: V loads issued right after the K-visible
//     barrier (hide under QK^T+softmax); K(kt+1) loads issued after the
//     V write (hide under PV). Raw s_barrier + explicit lgkmcnt(0) instead
//     of __syncthreads (whose vmcnt(0) drain would serialize the in-flight
//     loads). Same barrier count, same LDS layout.
//  2. safe_exp: libm expf -> __expf (v_exp_f32); ~180 calls/thread, args<=0.
// GEMMs unchanged from round 13 (all below the attn dispatches now).
// ---------------------------------------------------------------------------

using bf16x8 = __attribute__((ext_vector_type(8))) short;
using bf16x4 = __attribute__((ext_vector_type(4))) short;
using f32x4  = __attribute__((ext_vector_type(4))) float;

__device__ __forceinline__ float b2f(short s) {
    return __uint_as_float(((unsigned int)(unsigned short)s) << 16);
}
__device__ __forceinline__ short f2b(float f) {
    unsigned int u = __float_as_uint(f);
    u += 0x7fffu + ((u >> 16) & 1u);   // round-to-nearest-even
    return (short)(u >> 16);
}
__device__ __forceinline__ f32x4 mfma16(bf16x8 a, bf16x8 b, f32x4 c) {
    return __builtin_amdgcn_mfma_f32_16x16x32_bf16(a, b, c, 0, 0, 0);
}
// args are always <= 0 here (online-softmax differences); __expf -> v_exp_f32
__device__ __forceinline__ float safe_exp(float x) {
    return __expf((x <= 0.f) ? x : 0.f);
}
// gelu(v) = 0.5 v (1 + erf(v/sqrt2)); erf via A&S 7.1.25 (|err| <= 2.5e-5,
// branch-free: rcp + exp + 5 fma). 100x below bf16 output quantization.
__device__ __forceinline__ float fast_gelu(float v) {
    float z  = fabsf(v) * 0.70710678118f;
    float t  = __builtin_amdgcn_rcpf(fmaf(0.47047f, z, 1.f));
    float e  = __expf(-z * z);
    float p  = t * fmaf(t, fmaf(t, 0.7478556f, -0.0958798f), 0.3480242f);
    float er = fmaf(-p, e, 1.f);                  // erf(|z|)
    er = (v < 0.f) ? -er : er;
    return 0.5f * v * (1.f + er);
}
// async global->LDS, 16 B per lane; LDS dest = wave-uniform base + lane*16
__device__ __forceinline__ void load_lds16(const short* g, short* l) {
    __builtin_amdgcn_global_load_lds((const __attribute__((address_space(1))) void*)g,
                                     (__attribute__((address_space(3))) void*)l, 16, 0, 0);
}
// raw barrier: LDS writes made visible, but in-flight GLOBAL loads are NOT
// drained (unlike __syncthreads' s_waitcnt vmcnt(0)) — the T14 enabler.
__device__ __forceinline__ void barrier_lds_only() {
    asm volatile("s_waitcnt lgkmcnt(0)" ::: "memory");
    __builtin_amdgcn_s_barrier();
    asm volatile("" ::: "memory");
}
#define NEGF (-3.0e38f)

// ---------------------------------------------------------------------------
// fp32 -> bf16 elementwise convert (n multiple of 1024). grid n/1024, 256 thr
// ---------------------------------------------------------------------------
__global__ void cvt_f32_bf16(const float* __restrict__ in, short* __restrict__ out, int n) {
    int i = (blockIdx.x * 256 + threadIdx.x) * 4;
    f32x4 v = *(const f32x4*)(in + i);
    bf16x4 o;
#pragma unroll
    for (int j = 0; j < 4; ++j) o[j] = f2b(v[j]);
    *(bf16x4*)(out + i) = o;
}

// ---------------------------------------------------------------------------
// fp32 in, bf16 transposed out: out[c][r] = in[r][c], in is R x C.
// grid (C/32, R/32), block (32,8)
// ---------------------------------------------------------------------------
__global__ void cvt_transpose(const float* __restrict__ in, short* __restrict__ out,
                              int R, int C) {
    __shared__ short tile[32][33];
    int bx = blockIdx.x * 32, by = blockIdx.y * 32;
    int tx = threadIdx.x, ty = threadIdx.y;
    for (int i = ty; i < 32; i += 8)
        tile[i][tx] = f2b(in[(size_t)(by + i) * C + bx + tx]);
    __syncthreads();
    for (int i = ty; i < 32; i += 8)
        out[(size_t)(bx + i) * R + by + tx] = tile[tx][i];
}

// wq/wk/wv (each 1024x1024 fp32) -> WQKVT (3072x1024 bf16, = [wq^T;wk^T;wv^T])
__global__ void cvt_transpose_qkv(const float* __restrict__ wq, const float* __restrict__ wk,
                                  const float* __restrict__ wv, short* __restrict__ out) {
    __shared__ short tile[32][33];
    const float* in = (blockIdx.z == 0) ? wq : (blockIdx.z == 1) ? wk : wv;
    short* dst = out + (size_t)blockIdx.z * 1024 * 1024;
    int bx = blockIdx.x * 32, by = blockIdx.y * 32;
    int tx = threadIdx.x, ty = threadIdx.y;
    for (int i = ty; i < 32; i += 8)
        tile[i][tx] = f2b(in[(size_t)(by + i) * 1024 + bx + tx]);
    __syncthreads();
    for (int i = ty; i < 32; i += 8)
        dst[(size_t)(bx + i) * 1024 + by + tx] = tile[tx][i];
}

// ---------------------------------------------------------------------------
// GEMM 128x128, BK=64, XOR-swizzled LDS k-chunks. NATURAL block order.
// mode 0: QKV — bias by col segment, Q scaled, V staged+transposed -> Vt
// mode 1: C = bf16(gelu(acc + bias0[col]))
// Epilogue always stages the tile in LDS, then coalesced 16-B stores.
// ---------------------------------------------------------------------------
__global__ __launch_bounds__(256, 4) void gemm_bt(
    const short* __restrict__ A, const short* __restrict__ Bt,
    const float* __restrict__ bias0, const float* __restrict__ bias1,
    const float* __restrict__ bias2,
    short* __restrict__ C, short* __restrict__ Vt,
    int M, int N, int K, float scale, int mode)
{
    __shared__ short sh[128 * 136];   // 34.8 KB; main loop uses first 16K shorts
    short* As = sh;
    short* Bs = sh + 8192;
    int m0 = blockIdx.x * 128, n0 = blockIdx.y * 128;
    int t = threadIdx.x;
    int wave = t >> 6, lane = t & 63, quad = lane >> 4, l16 = lane & 15;
    int wr = (wave >> 1) * 64, wc = (wave & 1) * 64;

    // staging pointers: 4 chunks per wave per buffer
    const short* ap[4]; const short* bp[4]; short* la[4]; short* lb[4];
    int gk = (((lane & 7) ^ (lane >> 3)) * 8);
#pragma unroll
    for (int l = 0; l < 4; ++l) {
        int c = wave * 4 + l;
        int row = c * 8 + (lane >> 3);
        ap[l] = A  + (size_t)(m0 + row) * K + gk;
        bp[l] = Bt + (size_t)(n0 + row) * K + gk;
        la[l] = As + c * 512;
        lb[l] = Bs + c * 512;
    }
    int sw = l16 & 7;   // frag-read swizzle key

    f32x4 acc[4][4] = {};
    for (int k0 = 0; k0 < K; k0 += 64) {
#pragma unroll
        for (int l = 0; l < 4; ++l) { load_lds16(ap[l] + k0, la[l]); load_lds16(bp[l] + k0, lb[l]); }
        __syncthreads();
#pragma unroll
        for (int ks = 0; ks < 2; ++ks) {
            int slot = ((ks * 4 + quad) ^ sw) * 8;
            bf16x8 af[4], bfr[4];
#pragma unroll
            for (int i = 0; i < 4; ++i)
                af[i] = *(bf16x8*)(As + (wr + i * 16 + l16) * 64 + slot);
#pragma unroll
            for (int j = 0; j < 4; ++j)
                bfr[j] = *(bf16x8*)(Bs + (wc + j * 16 + l16) * 64 + slot);
#pragma unroll
            for (int i = 0; i < 4; ++i)
#pragma unroll
                for (int j = 0; j < 4; ++j)
                    acc[i][j] = mfma16(af[i], bfr[j], acc[i][j]);
        }
        __syncthreads();
    }
    // after final barrier, all LDS reads are done -> sh reusable for staging

    int seg0 = n0 >> 10;   // tiles are 128-aligned: never straddle a segment
    if (mode == 1 || seg0 < 2) {
        // ---- stage bf16 tile in LDS: sh[row*136 + col], row/col in [0,128)
        if (mode == 1) {
#pragma unroll
            for (int j = 0; j < 4; ++j) {
                int col = n0 + wc + j * 16 + l16;
                float bs = bias0[col];
#pragma unroll
                for (int i = 0; i < 4; ++i)
#pragma unroll
                    for (int r = 0; r < 4; ++r) {
                        float v = fast_gelu(acc[i][j][r] + bs);
                        sh[(wr + i * 16 + quad * 4 + r) * 136 + wc + j * 16 + l16] = f2b(v);
                    }
            }
        } else {
            float sc = (seg0 == 0) ? scale : 1.0f;
            const float* bpt = (seg0 == 0) ? bias0 : bias1;
#pragma unroll
            for (int j = 0; j < 4; ++j) {
                int col = n0 + wc + j * 16 + l16;
                float bs = bpt[col & 1023];
#pragma unroll
                for (int i = 0; i < 4; ++i)
#pragma unroll
                    for (int r = 0; r < 4; ++r)
                        sh[(wr + i * 16 + quad * 4 + r) * 136 + wc + j * 16 + l16] =
                            f2b((acc[i][j][r] + bs) * sc);
            }
        }
        __syncthreads();
        // ---- coalesced write-out: 2 threads per row, 8 x 16 B each
        int row = t >> 1, half = t & 1;
        const short* src = sh + row * 136 + half * 64;
        short* dst = C + (size_t)(m0 + row) * N + n0 + half * 64;
#pragma unroll
        for (int cgk = 0; cgk < 8; ++cgk)
            *(bf16x8*)(dst + cgk * 8) = *(const bf16x8*)(src + cgk * 8);
    } else {
        // ---- V part: stage TRANSPOSED in LDS (sh[c*136 + row]), then write
        //      Vt (b, h, d, s) with 16-B chunks coalesced along s.
#pragma unroll
        for (int j = 0; j < 4; ++j) {
            int cl = wc + j * 16 + l16;                 // local col in [0,128)
            float bs = bias2[(n0 & 1023) + cl];
#pragma unroll
            for (int i = 0; i < 4; ++i)
#pragma unroll
                for (int r = 0; r < 4; ++r)
                    sh[cl * 136 + wr + i * 16 + quad * 4 + r] = f2b(acc[i][j][r] + bs);
        }
        __syncthreads();
        int h0 = (n0 & 1023) >> 6;                      // first head of tile
        int bb = m0 >> 11, s0 = m0 & 2047;
        int sc = t & 15;                                // s-chunk within tile
#pragma unroll
        for (int cgk = 0; cgk < 8; ++cgk) {
            int cl = (t >> 4) + cgk * 16;               // local col
            int h = h0 + (cl >> 6), d = cl & 63;
            *(bf16x8*)(Vt + (((size_t)(bb * 16 + h)) * 64 + d) * 2048 + s0 + sc * 8) =
                *(const bf16x8*)(sh + cl * 136 + sc * 8);
        }
    }
}

// ---------------------------------------------------------------------------
// MLP2 GEMM: 128x64 tile, BK=64, wave owns 64x32 (acc[4][2]). Double-buffered,
// counted vmcnt(6). Natural block order. Cf = A@B + bias + resf (fp32 out).
// grid (M/128, N/64), 256 thr, 48 KB LDS.
// ---------------------------------------------------------------------------
__global__ __launch_bounds__(256, 2) void gemm128x64_db(
    const short* __restrict__ A, const short* __restrict__ Bt,
    const float* __restrict__ bias, const float* __restrict__ resf,
    float* __restrict__ Cf, int M, int N, int K)
{
    __shared__ short As[2][128 * 64];
    __shared__ short Bs[2][64 * 64];
    int m0 = blockIdx.x * 128, n0 = blockIdx.y * 64;
    int t = threadIdx.x;
    int wave = t >> 6, lane = t & 63, quad = lane >> 4, l16 = lane & 15;
    int wr = (wave >> 1) * 64, wc = (wave & 1) * 32;

    const short* ap[4]; const short* bp[2]; int loA[4], loB[2];
    int gk = (((lane & 7) ^ (lane >> 3)) * 8);
#pragma unroll
    for (int l = 0; l < 4; ++l) {
        int c = wave * 4 + l;                 // A-chunks 0..15
        int row = c * 8 + (lane >> 3);
        ap[l] = A + (size_t)(m0 + row) * K + gk;
        loA[l] = c * 512;
    }
#pragma unroll
    for (int l = 0; l < 2; ++l) {
        int c = wave * 2 + l;                 // B-chunks 0..7
        int row = c * 8 + (lane >> 3);
        bp[l] = Bt + (size_t)(n0 + row) * K + gk;
        loB[l] = c * 512;
    }
    int sw = l16 & 7;

    const int nt = K >> 6;
    // prologue: stage tile 0
#pragma unroll
    for (int l = 0; l < 4; ++l) load_lds16(ap[l], &As[0][loA[l]]);
#pragma unroll
    for (int l = 0; l < 2; ++l) load_lds16(bp[l], &Bs[0][loB[l]]);

    f32x4 acc[4][2] = {};
    for (int ti = 0; ti < nt; ++ti) {
        int cur = ti & 1;
        if (ti + 1 < nt) {
            int k0 = (ti + 1) << 6;
#pragma unroll
            for (int l = 0; l < 4; ++l) load_lds16(ap[l] + k0, &As[cur ^ 1][loA[l]]);
#pragma unroll
            for (int l = 0; l < 2; ++l) load_lds16(bp[l] + k0, &Bs[cur ^ 1][loB[l]]);
            asm volatile("s_waitcnt vmcnt(6)" ::: "memory");  // drain cur's 6 only
        } else {
            asm volatile("s_waitcnt vmcnt(0)" ::: "memory");
        }
        __builtin_amdgcn_s_barrier();
        asm volatile("" ::: "memory");

        const short* as = &As[cur][0];
        const short* bs = &Bs[cur][0];
#pragma unroll
        for (int ks = 0; ks < 2; ++ks) {
            int slot = ((ks * 4 + quad) ^ sw) * 8;
            bf16x8 af[4], bfr[2];
#pragma unroll
            for (int i = 0; i < 4; ++i)
                af[i] = *(bf16x8*)(as + (wr + i * 16 + l16) * 64 + slot);
#pragma unroll
            for (int j = 0; j < 2; ++j)
                bfr[j] = *(bf16x8*)(bs + (wc + j * 16 + l16) * 64 + slot);
#pragma unroll
            for (int i = 0; i < 4; ++i)
#pragma unroll
                for (int j = 0; j < 2; ++j)
                    acc[i][j] = mfma16(af[i], bfr[j], acc[i][j]);
        }
        asm volatile("" ::: "memory");
        __builtin_amdgcn_s_barrier();   // protect buf cur^1 before next stage
    }

#pragma unroll
    for (int j = 0; j < 2; ++j) {
        int col = n0 + wc + j * 16 + l16;
        float bs = bias[col];
#pragma unroll
        for (int i = 0; i < 4; ++i) {
#pragma unroll
            for (int r = 0; r < 4; ++r) {
                int row = m0 + wr + i * 16 + quad * 4 + r;
                Cf[(size_t)row * N + col] = acc[i][j][r] + bs + resf[(size_t)row * N + col];
            }
        }
    }
}

// ---------------------------------------------------------------------------
// Windowed attention with global column. Round-14: T14 async staging —
// V loads issued before QK^T (land during softmax), K(kt+1) loads issued
// before PV (land during PV). barrier_lds_only keeps them in flight.
// ---------------------------------------------------------------------------
__global__ __launch_bounds__(256, 2) void attn_kernel(
    const short* __restrict__ QKV, const short* __restrict__ Vt,
    const int* __restrict__ mask,
    const float* __restrict__ bk, const float* __restrict__ bv,
    short* __restrict__ attn)
{
    extern __shared__ char smem[];
    short* PsQ = (short*)smem;
    short* KV  = (short*)(smem + 34816);
    float* gkf = (float*)(smem + 53248);
    float* gvf = (float*)(smem + 53504);

    int blk = blockIdx.x;
    int c = blk & 15, h = (blk >> 4) & 15, b = blk >> 8;
    int t = threadIdx.x;
    int wave = t >> 6, lane = t & 63, quad = lane >> 4, l16 = lane & 15;
    int q0 = c * 128;
    const int bs_off = b * 2048;
    const short* Q = QKV + h * 64;
    const short* K = QKV + 1024 + h * 64;
    const short* Vg = Vt + (size_t)(b * 16 + h) * 64 * 2048;

#pragma unroll
    for (int l = 0; l < 4; ++l) {
        int idx = l * 256 + t;
        int p = idx >> 3, dc = (idx & 7) * 8;
        *(bf16x8*)(PsQ + p * 72 + dc) =
            *(const bf16x8*)(Q + ((size_t)(bs_off + q0 + p)) * 3072 + dc);
    }
    if (t < 64) { gkf[t] = bk[h * 64 + t]; gvf[t] = bv[h * 64 + t]; }
    __syncthreads();

    bf16x8 aq[2][2];
#pragma unroll
    for (int ti = 0; ti < 2; ++ti)
#pragma unroll
        for (int ks = 0; ks < 2; ++ks)
            aq[ti][ks] = *(bf16x8*)(PsQ + (wave * 32 + ti * 16 + l16) * 72 + ks * 32 + quad * 8);

    float s_g[2][4];
#pragma unroll
    for (int ti = 0; ti < 2; ++ti)
#pragma unroll
        for (int r = 0; r < 4; ++r) {
            int row = wave * 32 + ti * 16 + quad * 4 + r;
            float part = 0.f;
#pragma unroll
            for (int dd = 0; dd < 4; ++dd) {
                int d = l16 * 4 + dd;
                part += b2f(PsQ[row * 72 + d]) * gkf[d];
            }
#pragma unroll
            for (int dsh = 1; dsh < 16; dsh <<= 1) part += __shfl_xor(part, dsh);
            s_g[ti][r] = part;
        }

    f32x4 o_acc[2][4] = {};
    float m_run[2][4], l_run[2][4];
#pragma unroll
    for (int ti = 0; ti < 2; ++ti)
#pragma unroll
        for (int r = 0; r < 4; ++r) { m_run[ti][r] = NEGF; l_run[ti][r] = 0.f; }

    int kt_beg = (q0 == 0) ? 1 : 0;
    int kt_end = (q0 + 256 > 2048) ? 2 : 3;

    bf16x8 kreg[4], vreg[4];
    // prologue: issue K loads for the first tile
    {
        int jb = q0 + (kt_beg - 1) * 128;
#pragma unroll
        for (int l = 0; l < 4; ++l) {
            int idx = l * 256 + t;
            kreg[l] = *(const bf16x8*)(K + ((size_t)(bs_off + jb + (idx >> 3))) * 3072 + (idx & 7) * 8);
        }
    }

    for (int kt = kt_beg; kt < kt_end; ++kt) {
        int jb = q0 + (kt - 1) * 128;
        // 1. K regs -> LDS (compiler waits vmcnt on kreg; hidden under prev PV)
#pragma unroll
        for (int l = 0; l < 4; ++l) {
            int idx = l * 256 + t;
            *(bf16x8*)(KV + (idx >> 3) * 72 + (idx & 7) * 8) = kreg[l];
        }
        // 2. issue V loads (land during QK^T + softmax)
#pragma unroll
        for (int l = 0; l < 4; ++l) {
            int idx = l * 256 + t;
            vreg[l] = *(const bf16x8*)(Vg + ((size_t)(idx >> 4)) * 2048 + jb + (idx & 15) * 8);
        }
        barrier_lds_only();   // K visible; V loads stay in flight

        f32x4 s_acc[2][8] = {};
#pragma unroll
        for (int ks = 0; ks < 2; ++ks) {
            bf16x8 bk8[8];
#pragma unroll
            for (int tj = 0; tj < 8; ++tj)
                bk8[tj] = *(bf16x8*)(KV + (tj * 16 + l16) * 72 + ks * 32 + quad * 8);
#pragma unroll
            for (int ti = 0; ti < 2; ++ti)
#pragma unroll
                for (int tj = 0; tj < 8; ++tj)
                    s_acc[ti][tj] = mfma16(aq[ti][ks], bk8[tj], s_acc[ti][tj]);
        }

        float negj[8]; int jcol[8];
#pragma unroll
        for (int tj = 0; tj < 8; ++tj) {
            jcol[tj] = jb + tj * 16 + l16;
            negj[tj] = (mask[bs_off + jcol[tj]] != 0) ? NEGF : 0.f;
        }
        float tmax[2][4];
#pragma unroll
        for (int ti = 0; ti < 2; ++ti)
#pragma unroll
            for (int r = 0; r < 4; ++r) tmax[ti][r] = NEGF;
#pragma unroll
        for (int ti = 0; ti < 2; ++ti) {
            int irow_base = q0 + wave * 32 + ti * 16 + quad * 4;
#pragma unroll
            for (int tj = 0; tj < 8; ++tj)
#pragma unroll
                for (int r = 0; r < 4; ++r) {
                    int dj = jcol[tj] - (irow_base + r);
                    float sc = (dj >= -128 && dj <= 128) ? (s_acc[ti][tj][r] + negj[tj]) : NEGF;
                    s_acc[ti][tj][r] = sc;
                    tmax[ti][r] = fmaxf(tmax[ti][r], sc);
                }
        }
#pragma unroll
        for (int ti = 0; ti < 2; ++ti)
#pragma unroll
            for (int r = 0; r < 4; ++r)
#pragma unroll
                for (int dsh = 1; dsh < 16; dsh <<= 1)
                    tmax[ti][r] = fmaxf(tmax[ti][r], __shfl_xor(tmax[ti][r], dsh));

        float alpha[2][4], lsum[2][4];
#pragma unroll
        for (int ti = 0; ti < 2; ++ti)
#pragma unroll
            for (int r = 0; r < 4; ++r) {
                float mnew = fmaxf(m_run[ti][r], tmax[ti][r]);
                alpha[ti][r] = safe_exp(m_run[ti][r] - mnew);
                m_run[ti][r] = mnew;
                lsum[ti][r] = 0.f;
            }
#pragma unroll
        for (int ti = 0; ti < 2; ++ti)
#pragma unroll
            for (int tj = 0; tj < 8; ++tj)
#pragma unroll
                for (int r = 0; r < 4; ++r) {
                    float p = safe_exp(s_acc[ti][tj][r] - m_run[ti][r]);
                    lsum[ti][r] += p;
                    PsQ[(wave * 32 + ti * 16 + quad * 4 + r) * 136 + tj * 16 + l16] = f2b(p);
                }
#pragma unroll
        for (int ti = 0; ti < 2; ++ti)
#pragma unroll
            for (int r = 0; r < 4; ++r) {
#pragma unroll
                for (int dsh = 1; dsh < 16; dsh <<= 1) lsum[ti][r] += __shfl_xor(lsum[ti][r], dsh);
                l_run[ti][r] = l_run[ti][r] * alpha[ti][r] + lsum[ti][r];
            }
#pragma unroll
        for (int ti = 0; ti < 2; ++ti)
#pragma unroll
            for (int dj = 0; dj < 4; ++dj)
#pragma unroll
                for (int r = 0; r < 4; ++r) o_acc[ti][dj][r] *= alpha[ti][r];

        barrier_lds_only();   // all waves done reading KV-as-K

        // 6. V regs -> LDS (compiler waits vmcnt on vreg; hidden under softmax)
#pragma unroll
        for (int l = 0; l < 4; ++l) {
            int idx = l * 256 + t;
            *(bf16x8*)(KV + (idx >> 4) * 136 + (idx & 15) * 8) = vreg[l];
        }
        // 7. issue K loads for next tile (land during PV)
        if (kt + 1 < kt_end) {
            int jb2 = q0 + kt * 128;
#pragma unroll
            for (int l = 0; l < 4; ++l) {
                int idx = l * 256 + t;
                kreg[l] = *(const bf16x8*)(K + ((size_t)(bs_off + jb2 + (idx >> 3))) * 3072 + (idx & 7) * 8);
            }
        }
        barrier_lds_only();   // V visible; K loads stay in flight

#pragma unroll
        for (int ks = 0; ks < 4; ++ks) {
            bf16x8 ap[2], bv8[4];
#pragma unroll
            for (int ti = 0; ti < 2; ++ti)
                ap[ti] = *(bf16x8*)(PsQ + (wave * 32 + ti * 16 + l16) * 136 + ks * 32 + quad * 8);
#pragma unroll
            for (int dj = 0; dj < 4; ++dj)
                bv8[dj] = *(bf16x8*)(KV + (dj * 16 + l16) * 136 + ks * 32 + quad * 8);
#pragma unroll
            for (int ti = 0; ti < 2; ++ti)
#pragma unroll
                for (int dj = 0; dj < 4; ++dj)
                    o_acc[ti][dj] = mfma16(ap[ti], bv8[dj], o_acc[ti][dj]);
        }
        barrier_lds_only();   // all waves done reading KV-as-V (next K write)
    }

#pragma unroll
    for (int ti = 0; ti < 2; ++ti) {
        int irow_base = q0 + wave * 32 + ti * 16 + quad * 4;
#pragma unroll
        for (int r = 0; r < 4; ++r) {
            int i = irow_base + r;
            float m2 = fmaxf(m_run[ti][r], s_g[ti][r]);
            float pg = safe_exp(s_g[ti][r] - m2);
            float al = safe_exp(m_run[ti][r] - m2);
            float l2 = l_run[ti][r] * al + pg;
            float invl = 1.f / fmaxf(l2, 1e-30f);
            float qm = (mask[bs_off + i] > 0) ? 0.f : 1.f;
#pragma unroll
            for (int dj = 0; dj < 4; ++dj) {
                int d = dj * 16 + l16;
                float val = (o_acc[ti][dj][r] * al + pg * gvf[d]) * invl * qm;
                attn[((size_t)(bs_off + i)) * 1024 + h * 64 + d] = f2b(val);
            }
        }
    }
}

// ---------------------------------------------------------------------------
// y = LN(x + attn) * g + b ; writes bf16 (GEMM input) AND fp32 (residual).
// ---------------------------------------------------------------------------
__global__ __launch_bounds__(256) void resid_ln(
    const float* __restrict__ x, const short* __restrict__ attn,
    const float* __restrict__ g, const float* __restrict__ be,
    short* __restrict__ yb, float* __restrict__ yf)
{
    int row = blockIdx.x, t = threadIdx.x;
    int lane = t & 63, wave = t >> 6;
    const size_t base = (size_t)row * 1024;
    float v[4]; float s = 0.f, s2 = 0.f;
#pragma unroll
    for (int i = 0; i < 4; ++i) {
        int c = i * 256 + t;
        float val = x[base + c] + b2f(attn[base + c]);
        v[i] = val; s += val; s2 += val * val;
    }
#pragma unroll
    for (int off = 32; off > 0; off >>= 1) { s += __shfl_xor(s, off); s2 += __shfl_xor(s2, off); }
    __shared__ float red[8];
    if (lane == 0) { red[wave] = s; red[4 + wave] = s2; }
    __syncthreads();
    s  = red[0] + red[1] + red[2] + red[3];
    s2 = red[4] + red[5] + red[6] + red[7];
    float mu  = s * (1.f / 1024.f);
    float var = s2 * (1.f / 1024.f) - mu * mu;
    float inv = rsqrtf(fmaxf(var, 0.f) + 1e-5f);
#pragma unroll
    for (int i = 0; i < 4; ++i) {
        int c = i * 256 + t;
        float o = (v[i] - mu) * inv * g[c] + be[c];
        yb[base + c] = f2b(o);
        yf[base + c] = o;
    }
}

// ---------------------------------------------------------------------------
// workspace layout, units = bf16 elements (2 B). total 47M units = 94 MB.
// ---------------------------------------------------------------------------
static constexpr size_t MEG      = 1048576;
static constexpr size_t OFF_WQKV = 0;            // 3M  (3072x1024 bf16)
static constexpr size_t OFF_W1T  = 3 * MEG;      // 4M
static constexpr size_t OFF_W2T  = 7 * MEG;      // 4M
static constexpr size_t OFF_XB   = 11 * MEG;     // 4M
static constexpr size_t OFF_QKV  = 15 * MEG;     // 12M (4096x3072 bf16; V third unused)
static constexpr size_t OFF_VT   = 27 * MEG;     // 4M
static constexpr size_t OFF_ATT  = 31 * MEG;     // 4M
static constexpr size_t OFF_YN   = 35 * MEG;     // 4M (bf16)
static constexpr size_t OFF_YF   = 39 * MEG;     // 8M units = 4M fp32
static constexpr size_t OFF_H    = OFF_QKV;      // 16M, aliases QKV+VT (dead)

extern "C" void kernel_launch(void* const* d_in, const int* in_sizes, int n_in,
                              void* d_out, int out_size, void* d_ws, size_t ws_size,
                              hipStream_t stream) {
    (void)in_sizes; (void)n_in; (void)out_size; (void)ws_size;
    const float* x    = (const float*)d_in[0];
    const int*   mask = (const int*)  d_in[1];
    const float* wq   = (const float*)d_in[2];
    const float* bq   = (const float*)d_in[3];
    const float* wk   = (const float*)d_in[4];
    const float* bk   = (const float*)d_in[5];
    const float* wv   = (const float*)d_in[6];
    const float* bv   = (const float*)d_in[7];
    // d_in[8..13] (global-query branch) are provably dead for the output
    const float* lng  = (const float*)d_in[14];
    const float* lnb  = (const float*)d_in[15];
    const float* w1   = (const float*)d_in[16];
    const float* b1   = (const float*)d_in[17];
    const float* w2   = (const float*)d_in[18];
    const float* b2   = (const float*)d_in[19];
    short* ws  = (short*)d_ws;
    float* out = (float*)d_out;

    dim3 tb(32, 8);
    cvt_transpose_qkv<<<dim3(32, 32, 3), tb, 0, stream>>>(wq, wk, wv, ws + OFF_WQKV);
    cvt_transpose<<<dim3(128, 32), tb, 0, stream>>>(w1, ws + OFF_W1T, 1024, 4096);
    cvt_transpose<<<dim3(32, 128), tb, 0, stream>>>(w2, ws + OFF_W2T, 4096, 1024);
    cvt_f32_bf16<<<4096, 256, 0, stream>>>(x, ws + OFF_XB, 4194304);

    // QKV = x @ [wq|wk|wv] + [bq|bk|bv]; Q scaled 1/8; V staged -> Vt fused
    gemm_bt<<<dim3(32, 24), 256, 0, stream>>>(ws + OFF_XB, ws + OFF_WQKV,
                                              bq, bk, bv,
                                              ws + OFF_QKV, ws + OFF_VT,
                                              4096, 3072, 1024, 0.125f, 0);

    attn_kernel<<<512, 256, 53760, stream>>>(ws + OFF_QKV, ws + OFF_VT,
                                             mask, bk, bv, ws + OFF_ATT);

    resid_ln<<<4096, 256, 0, stream>>>(x, ws + OFF_ATT, lng, lnb,
                                       ws + OFF_YN, (float*)(ws + OFF_YF));

    // h = gelu(y@w1 + b1)
    gemm_bt<<<dim3(32, 32), 256, 0, stream>>>(ws + OFF_YN, ws + OFF_W1T,
                                              b1, nullptr, nullptr,
                                              ws + OFF_H, nullptr,
                                              4096, 4096, 1024, 1.0f, 1);
    // out = y + h@w2 + b2 (128x64 tile, wave=64x32, dbuf + counted vmcnt(6))
    gemm128x64_db<<<dim3(32, 16), 256, 0, stream>>>(ws + OFF_H, ws + OFF_W2T,
                                                    b2, (const float*)(ws + OFF_YF),
                                                    out, 4096, 1024, 4096);
}